// Round 1
// baseline (3416.565 us; speedup 1.0000x reference)
//
#include <hip/hip_runtime.h>

// Problem constants (match reference)
constexpr int B_  = 2;
constexpr int L_  = 1024;
constexpr int D_  = 768;
constexpr int E_  = 1536;
constexpr int N_  = 16;
constexpr int R_  = 48;
constexpr int NL_ = 4;
constexpr int NC_ = 5;
constexpr int M_  = B_ * L_;        // 2048 token rows
constexpr int E2_ = 2 * E_;         // 3072
constexpr int XD_ = R_ + 2 * N_;    // 80
constexpr float EPS_ = 1e-5f;

__device__ __forceinline__ float sigm(float x) { return 1.0f / (1.0f + __expf(-x)); }
__device__ __forceinline__ float softplusf(float x) { return x > 20.0f ? x : log1pf(__expf(x)); }

__device__ __forceinline__ float block_sum(float v, float* sm) {
  #pragma unroll
  for (int o = 32; o > 0; o >>= 1) v += __shfl_xor(v, o);
  if ((threadIdx.x & 63) == 0) sm[threadIdx.x >> 6] = v;
  __syncthreads();
  return sm[0] + sm[1] + sm[2] + sm[3];
}

// h[m,d] = x[m,:12] @ proj_w[d,:12] + proj_b[d]
__global__ __launch_bounds__(256) void k_proj(const float* __restrict__ x, const float* __restrict__ pw,
                                              const float* __restrict__ pb, float* __restrict__ h) {
  __shared__ float xs[12];
  int m = blockIdx.y;
  int d = blockIdx.x * 256 + threadIdx.x;
  if (threadIdx.x < 12) xs[threadIdx.x] = x[m * 12 + threadIdx.x];
  __syncthreads();
  float acc = pb[d];
  #pragma unroll
  for (int j = 0; j < 12; j++) acc = fmaf(xs[j], pw[d * 12 + j], acc);
  h[(size_t)m * D_ + d] = acc;
}

// hn[m,:] = rmsnorm(h[m,:]) * w   (one block per row, 768 = 256*3)
__global__ __launch_bounds__(256) void k_rmsnorm(const float* __restrict__ h, const float* __restrict__ w,
                                                 float* __restrict__ hn) {
  __shared__ float sm[4];
  int m = blockIdx.x, tid = threadIdx.x;
  const float* row = h + (size_t)m * D_;
  float v0 = row[tid], v1 = row[tid + 256], v2 = row[tid + 512];
  float s = block_sum(v0 * v0 + v1 * v1 + v2 * v2, sm);
  float sc = rsqrtf(s * (1.0f / D_) + EPS_);
  float* o = hn + (size_t)m * D_;
  o[tid]       = v0 * sc * w[tid];
  o[tid + 256] = v1 * sc * w[tid + 256];
  o[tid + 512] = v2 * sc * w[tid + 512];
}

// C[M,N] = A[M,K] @ Bw[N,K]^T (+ res).  64x64 tile, 256 thr, 4x4 per thread.
template <int RES>
__global__ __launch_bounds__(256) void k_gemm(const float* __restrict__ A, const float* __restrict__ Bw,
                                              float* __restrict__ C, const float* __restrict__ res,
                                              int Kd, int Nd) {
  __shared__ float As[16][68];
  __shared__ float Bs[16][68];
  const int tid = threadIdx.x;
  const int tx = tid & 15, ty = tid >> 4;
  const int m0 = blockIdx.y << 6, n0 = blockIdx.x << 6;
  const int lr = tid >> 2;          // 0..63
  const int lk = (tid & 3) << 2;    // 0,4,8,12
  const float* Ap = A + (size_t)(m0 + lr) * Kd + lk;
  const float* Bp = Bw + (size_t)(n0 + lr) * Kd + lk;
  float acc[4][4] = {};
  for (int k0 = 0; k0 < Kd; k0 += 16) {
    float4 av = *(const float4*)(Ap + k0);
    float4 bv = *(const float4*)(Bp + k0);
    As[lk + 0][lr] = av.x; As[lk + 1][lr] = av.y; As[lk + 2][lr] = av.z; As[lk + 3][lr] = av.w;
    Bs[lk + 0][lr] = bv.x; Bs[lk + 1][lr] = bv.y; Bs[lk + 2][lr] = bv.z; Bs[lk + 3][lr] = bv.w;
    __syncthreads();
    #pragma unroll
    for (int k = 0; k < 16; k++) {
      float4 a = *(const float4*)&As[k][ty << 2];
      float4 b = *(const float4*)&Bs[k][tx << 2];
      float ar[4] = {a.x, a.y, a.z, a.w};
      float br[4] = {b.x, b.y, b.z, b.w};
      #pragma unroll
      for (int i = 0; i < 4; i++)
        #pragma unroll
        for (int j = 0; j < 4; j++) acc[i][j] = fmaf(ar[i], br[j], acc[i][j]);
    }
    __syncthreads();
  }
  #pragma unroll
  for (int i = 0; i < 4; i++) {
    size_t off = (size_t)(m0 + (ty << 2) + i) * Nd + n0 + (tx << 2);
    float4 v = make_float4(acc[i][0], acc[i][1], acc[i][2], acc[i][3]);
    if (RES) {
      float4 r = *(const float4*)(res + off);
      v.x += r.x; v.y += r.y; v.z += r.z; v.w += r.w;
    }
    *(float4*)(C + off) = v;
  }
}

// u[m,e] = silu( conv_b[e] + sum_k conv_w[e,k]*proj_u[b, t+k-3, e] )
__global__ __launch_bounds__(256) void k_conv(const float* __restrict__ proj, const float* __restrict__ cw,
                                              const float* __restrict__ cb, float* __restrict__ u) {
  int m = blockIdx.y;
  int b = m >> 10, t = m & (L_ - 1);
  int e = blockIdx.x * 256 + threadIdx.x;
  float4 w = *(const float4*)(cw + e * 4);
  float wr[4] = {w.x, w.y, w.z, w.w};
  float acc = cb[e];
  #pragma unroll
  for (int k = 0; k < 4; k++) {
    int tt = t + k - 3;
    if (tt >= 0) acc = fmaf(wr[k], proj[(size_t)(b * L_ + tt) * E2_ + e], acc);
  }
  u[(size_t)m * E_ + e] = acc * sigm(acc);
}

// xdbc[m, 0:80] = u[m,:] @ xproj_w[80, E]^T   (one block per row; wave-dot)
__global__ __launch_bounds__(256) void k_xproj(const float* __restrict__ u, const float* __restrict__ w,
                                               float* __restrict__ xdbc) {
  __shared__ float us[E_];
  int m = blockIdx.x;
  for (int i = threadIdx.x; i < E_; i += 256) us[i] = u[(size_t)m * E_ + i];
  __syncthreads();
  int wv = threadIdx.x >> 6, ln = threadIdx.x & 63;
  for (int n = wv; n < XD_; n += 4) {
    const float* wr = w + (size_t)n * E_;
    float s = 0.0f;
    for (int k = ln; k < E_; k += 64) s = fmaf(us[k], wr[k], s);
    #pragma unroll
    for (int o = 32; o > 0; o >>= 1) s += __shfl_xor(s, o);
    if (ln == 0) xdbc[(size_t)m * XD_ + n] = s;
  }
}

// dt[m,e] = softplus( xdbc[m,0:48] @ dt_w[e,0:48] + dt_b[e] )
__global__ __launch_bounds__(256) void k_dt(const float* __restrict__ xdbc, const float* __restrict__ dw,
                                            const float* __restrict__ db, float* __restrict__ dt) {
  __shared__ float xs[R_];
  int m = blockIdx.y;
  int e = blockIdx.x * 256 + threadIdx.x;
  if (threadIdx.x < R_) xs[threadIdx.x] = xdbc[(size_t)m * XD_ + threadIdx.x];
  __syncthreads();
  float acc = db[e];
  const float* wr = dw + (size_t)e * R_;
  #pragma unroll
  for (int k = 0; k < R_; k += 4) {
    float4 wv = *(const float4*)(wr + k);
    acc = fmaf(xs[k], wv.x, acc);
    acc = fmaf(xs[k + 1], wv.y, acc);
    acc = fmaf(xs[k + 2], wv.z, acc);
    acc = fmaf(xs[k + 3], wv.w, acc);
  }
  dt[(size_t)m * E_ + e] = softplusf(acc);
}

// Selective scan: thread per (b,e,n); n = lane%16; y includes +u*D and *silu(gate)
__global__ __launch_bounds__(256) void k_scan(const float* __restrict__ u, const float* __restrict__ dt,
                                              const float* __restrict__ xdbc, const float* __restrict__ proj,
                                              const float* __restrict__ A_log, const float* __restrict__ Dp,
                                              float* __restrict__ y) {
  const int n = threadIdx.x & (N_ - 1);
  const int e = blockIdx.x * 16 + (threadIdx.x >> 4);
  const int b = blockIdx.y;
  const float A = -__expf(A_log[e * N_ + n]);
  const float Dv = Dp[e];
  float hs = 0.0f;
  int m = b * L_;
  float dt_c = dt[(size_t)m * E_ + e];
  float u_c  = u[(size_t)m * E_ + e];
  float B_c  = xdbc[(size_t)m * XD_ + R_ + n];
  float C_c  = xdbc[(size_t)m * XD_ + R_ + N_ + n];
  float g_c  = proj[(size_t)m * E2_ + E_ + e];
  for (int t = 0; t < L_; t++) {
    float dt_n = 0, u_n = 0, B_n = 0, C_n = 0, g_n = 0;
    if (t + 1 < L_) {
      int mn = m + 1;
      dt_n = dt[(size_t)mn * E_ + e];
      u_n  = u[(size_t)mn * E_ + e];
      B_n  = xdbc[(size_t)mn * XD_ + R_ + n];
      C_n  = xdbc[(size_t)mn * XD_ + R_ + N_ + n];
      g_n  = proj[(size_t)mn * E2_ + E_ + e];
    }
    float dA = __expf(dt_c * A);
    hs = fmaf(hs, dA, dt_c * B_c * u_c);
    float p = hs * C_c;
    p += __shfl_xor(p, 1); p += __shfl_xor(p, 2); p += __shfl_xor(p, 4); p += __shfl_xor(p, 8);
    if (n == 0) {
      float g = g_c;
      y[(size_t)m * E_ + e] = (p + u_c * Dv) * (g * sigm(g));
    }
    m++; dt_c = dt_n; u_c = u_n; B_c = B_n; C_c = C_n; g_c = g_n;
  }
}

// rs[m] = rsqrt(mean(h[m,:]^2)+eps)  (final norm row scales)
__global__ __launch_bounds__(256) void k_rowscale(const float* __restrict__ h, float* __restrict__ rs) {
  __shared__ float sm[4];
  int m = blockIdx.x, tid = threadIdx.x;
  const float* row = h + (size_t)m * D_;
  float v0 = row[tid], v1 = row[tid + 256], v2 = row[tid + 512];
  float s = block_sum(v0 * v0 + v1 * v1 + v2 * v2, sm);
  if (tid == 0) rs[m] = rsqrtf(s * (1.0f / D_) + EPS_);
}

// pooled[b,d] += fnorm_w[d]/L * sum_t h[b,t,d]*rs[b,t]   (t chunked, atomic)
__global__ __launch_bounds__(256) void k_pool(const float* __restrict__ h, const float* __restrict__ rs,
                                              const float* __restrict__ fw, float* __restrict__ pooled) {
  int d = blockIdx.x * 256 + threadIdx.x;
  int t0 = blockIdx.y * 128;
  int b = blockIdx.z;
  float acc = 0.0f;
  for (int t = t0; t < t0 + 128; t++) {
    int m = b * L_ + t;
    acc = fmaf(h[(size_t)m * D_ + d], rs[m], acc);
  }
  atomicAdd(&pooled[b * D_ + d], acc * fw[d] * (1.0f / L_));
}

// out[b,c] = pooled[b,:] @ cls_w[c,:] + cls_b[c]
__global__ __launch_bounds__(256) void k_logits(const float* __restrict__ pooled, const float* __restrict__ cw,
                                                const float* __restrict__ cb, float* __restrict__ out) {
  int wv = threadIdx.x >> 6, ln = threadIdx.x & 63;
  for (int p = wv; p < B_ * NC_; p += 4) {
    int b = p / NC_, c = p % NC_;
    float s = 0.0f;
    for (int d = ln; d < D_; d += 64) s = fmaf(pooled[b * D_ + d], cw[c * D_ + d], s);
    #pragma unroll
    for (int o = 32; o > 0; o >>= 1) s += __shfl_xor(s, o);
    if (ln == 0) out[p] = s + cb[c];
  }
}

extern "C" void kernel_launch(void* const* d_in, const int* in_sizes, int n_in,
                              void* d_out, int out_size, void* d_ws, size_t ws_size,
                              hipStream_t stream) {
  const float* x       = (const float*)d_in[0];
  const float* proj_w  = (const float*)d_in[1];
  const float* proj_b  = (const float*)d_in[2];
  const float* norm_w  = (const float*)d_in[3];
  const float* in_w    = (const float*)d_in[4];
  const float* conv_w  = (const float*)d_in[5];
  const float* conv_b  = (const float*)d_in[6];
  const float* xproj_w = (const float*)d_in[7];
  const float* dt_w    = (const float*)d_in[8];
  const float* dt_b    = (const float*)d_in[9];
  const float* A_log   = (const float*)d_in[10];
  const float* D_param = (const float*)d_in[11];
  const float* out_w   = (const float*)d_in[12];
  const float* fnorm_w = (const float*)d_in[13];
  const float* cls_w   = (const float*)d_in[14];
  const float* cls_b   = (const float*)d_in[15];
  float* out = (float*)d_out;

  float* ws = (float*)d_ws;
  // workspace layout (floats)
  float* h      = ws;                                   // M*D
  float* hn     = h + (size_t)M_ * D_;                  // M*D
  float* proj   = hn + (size_t)M_ * D_;                 // M*2E
  float* ub     = proj + (size_t)M_ * E2_;              // M*E
  float* xdbc   = ub + (size_t)M_ * E_;                 // M*80
  float* dtb    = xdbc + (size_t)M_ * XD_;              // M*E
  float* yb     = dtb + (size_t)M_ * E_;                // M*E
  float* rsb    = yb + (size_t)M_ * E_;                 // M
  float* pooled = rsb + M_;                             // B*D

  k_proj<<<dim3(D_ / 256, M_), 256, 0, stream>>>(x, proj_w, proj_b, h);

  for (int i = 0; i < NL_; i++) {
    const float* inw_i  = in_w + (size_t)i * E2_ * D_;
    const float* outw_i = out_w + (size_t)i * D_ * E_;
    k_rmsnorm<<<M_, 256, 0, stream>>>(h, norm_w + i * D_, hn);
    k_gemm<0><<<dim3(E2_ / 64, M_ / 64), 256, 0, stream>>>(hn, inw_i, proj, nullptr, D_, E2_);
    k_conv<<<dim3(E_ / 256, M_), 256, 0, stream>>>(proj, conv_w + i * E_ * 4, conv_b + i * E_, ub);
    k_xproj<<<M_, 256, 0, stream>>>(ub, xproj_w + (size_t)i * XD_ * E_, xdbc);
    k_dt<<<dim3(E_ / 256, M_), 256, 0, stream>>>(xdbc, dt_w + (size_t)i * E_ * R_, dt_b + i * E_, dtb);
    k_scan<<<dim3(E_ / 16, B_), 256, 0, stream>>>(ub, dtb, xdbc, proj,
                                                  A_log + (size_t)i * E_ * N_, D_param + i * E_, yb);
    k_gemm<1><<<dim3(D_ / 64, M_ / 64), 256, 0, stream>>>(yb, outw_i, h, h, E_, D_);
  }

  k_rowscale<<<M_, 256, 0, stream>>>(h, rsb);
  hipMemsetAsync(pooled, 0, (size_t)B_ * D_ * sizeof(float), stream);
  k_pool<<<dim3(D_ / 256, L_ / 128, B_), 256, 0, stream>>>(h, rsb, fnorm_w, pooled);
  k_logits<<<1, 256, 0, stream>>>(pooled, cls_w, cls_b, out);
}

// Round 2
// 2101.105 us; speedup vs baseline: 1.6261x; 1.6261x over previous
//
#include <hip/hip_runtime.h>

// Problem constants (match reference)
constexpr int B_  = 2;
constexpr int L_  = 1024;
constexpr int D_  = 768;
constexpr int E_  = 1536;
constexpr int N_  = 16;
constexpr int R_  = 48;
constexpr int NL_ = 4;
constexpr int NC_ = 5;
constexpr int M_  = B_ * L_;        // 2048 token rows
constexpr int E2_ = 2 * E_;         // 3072
constexpr int XD_ = R_ + 2 * N_;    // 80
constexpr float EPS_ = 1e-5f;

typedef __attribute__((ext_vector_type(8))) short bf16x8;
typedef __attribute__((ext_vector_type(4))) float f32x4;
typedef const __attribute__((address_space(1))) void* gas_t;
typedef __attribute__((address_space(3))) void* las_t;

__device__ __forceinline__ float sigm(float x) { return 1.0f / (1.0f + __expf(-x)); }
__device__ __forceinline__ float softplusf(float x) { return x > 20.0f ? x : log1pf(__expf(x)); }
__device__ __forceinline__ ushort f2b(float f) {  // fp32 -> bf16 RNE
  union { float f; unsigned u; } v; v.f = f;
  unsigned r = (v.u + 0x7fffu + ((v.u >> 16) & 1u)) >> 16;
  return (ushort)r;
}

__device__ __forceinline__ float block_sum(float v, float* sm) {
  #pragma unroll
  for (int o = 32; o > 0; o >>= 1) v += __shfl_xor(v, o);
  if ((threadIdx.x & 63) == 0) sm[threadIdx.x >> 6] = v;
  __syncthreads();
  return sm[0] + sm[1] + sm[2] + sm[3];
}

// fp32 -> bf16 bulk convert (weights), n multiple of 4
__global__ __launch_bounds__(256) void k_f2b(const float* __restrict__ s, ushort* __restrict__ d, int nv) {
  int i = (blockIdx.x * 256 + threadIdx.x) * 4;
  if (i >= nv) return;
  float4 v = *(const float4*)(s + i);
  ushort4 o = make_ushort4(f2b(v.x), f2b(v.y), f2b(v.z), f2b(v.w));
  *(ushort4*)(d + i) = o;
}

// h[m,d] = x[m,:12] @ proj_w[d,:12] + proj_b[d]
__global__ __launch_bounds__(256) void k_proj(const float* __restrict__ x, const float* __restrict__ pw,
                                              const float* __restrict__ pb, float* __restrict__ h) {
  __shared__ float xs[12];
  int m = blockIdx.y;
  int d = blockIdx.x * 256 + threadIdx.x;
  if (threadIdx.x < 12) xs[threadIdx.x] = x[m * 12 + threadIdx.x];
  __syncthreads();
  float acc = pb[d];
  #pragma unroll
  for (int j = 0; j < 12; j++) acc = fmaf(xs[j], pw[d * 12 + j], acc);
  h[(size_t)m * D_ + d] = acc;
}

// hn_bf16[m,:] = rmsnorm(h[m,:]) * w
__global__ __launch_bounds__(256) void k_rmsnorm_bf(const float* __restrict__ h, const float* __restrict__ w,
                                                    ushort* __restrict__ hn) {
  __shared__ float sm[4];
  int m = blockIdx.x, tid = threadIdx.x;
  const float* row = h + (size_t)m * D_;
  float v0 = row[tid], v1 = row[tid + 256], v2 = row[tid + 512];
  float s = block_sum(v0 * v0 + v1 * v1 + v2 * v2, sm);
  float sc = rsqrtf(s * (1.0f / D_) + EPS_);
  ushort* o = hn + (size_t)m * D_;
  o[tid]       = f2b(v0 * sc * w[tid]);
  o[tid + 256] = f2b(v1 * sc * w[tid + 256]);
  o[tid + 512] = f2b(v2 * sc * w[tid + 512]);
}

// C[M,Nd] = A_bf16[M,Kd] @ Bw_bf16[Nd,Kd]^T (+ res). MFMA 16x16x32 bf16.
// Block 256 thr = 4 waves (2x2 wave grid), tile BM x BN, BK=32.
// LDS layout [rows][32] bf16 row-major — matches global_load_lds wave-uniform+lane*16.
template <int BM, int BN, int RESID>
__global__ __launch_bounds__(256) void k_gemm_bf(const ushort* __restrict__ A, const ushort* __restrict__ Bw,
                                                 float* __restrict__ C, const float* __restrict__ res,
                                                 int Kd, int Nd) {
  constexpr int AM = BM / 32, BNF = BN / 32;
  __shared__ ushort sA[BM * 32];
  __shared__ ushort sB[BN * 32];
  const int tid = threadIdx.x;
  const int wave = tid >> 6, lane = tid & 63;
  const int q = lane >> 4, r = lane & 15;
  const int wm = wave >> 1, wn = wave & 1;
  const int m0 = blockIdx.y * BM, n0 = blockIdx.x * BN;
  f32x4 acc[AM][BNF] = {};

  for (int k0 = 0; k0 < Kd; k0 += 32) {
    #pragma unroll
    for (int j = 0; j < BM / 64; j++) {
      int i = j * 256 + tid;
      const ushort* gp = A + (size_t)(m0 + (i >> 2)) * Kd + k0 + ((i & 3) << 3);
      __builtin_amdgcn_global_load_lds((gas_t)gp, (las_t)(sA + ((j * 256 + wave * 64) << 3)), 16, 0, 0);
    }
    #pragma unroll
    for (int j = 0; j < BN / 64; j++) {
      int i = j * 256 + tid;
      const ushort* gp = Bw + (size_t)(n0 + (i >> 2)) * Kd + k0 + ((i & 3) << 3);
      __builtin_amdgcn_global_load_lds((gas_t)gp, (las_t)(sB + ((j * 256 + wave * 64) << 3)), 16, 0, 0);
    }
    __syncthreads();
    bf16x8 af[AM], bfv[BNF];
    #pragma unroll
    for (int mi = 0; mi < AM; mi++)
      af[mi] = *(const bf16x8*)&sA[(wm * (BM / 2) + mi * 16 + r) * 32 + q * 8];
    #pragma unroll
    for (int nj = 0; nj < BNF; nj++)
      bfv[nj] = *(const bf16x8*)&sB[(wn * (BN / 2) + nj * 16 + r) * 32 + q * 8];
    #pragma unroll
    for (int mi = 0; mi < AM; mi++)
      #pragma unroll
      for (int nj = 0; nj < BNF; nj++)
        acc[mi][nj] = __builtin_amdgcn_mfma_f32_16x16x32_bf16(af[mi], bfv[nj], acc[mi][nj], 0, 0, 0);
    __syncthreads();
  }
  // C/D layout: col = lane&15, row = (lane>>4)*4 + reg  [verified m89/m91]
  #pragma unroll
  for (int mi = 0; mi < AM; mi++) {
    #pragma unroll
    for (int nj = 0; nj < BNF; nj++) {
      int col = n0 + wn * (BN / 2) + nj * 16 + r;
      #pragma unroll
      for (int rg = 0; rg < 4; rg++) {
        int row = m0 + wm * (BM / 2) + mi * 16 + q * 4 + rg;
        size_t off = (size_t)row * Nd + col;
        float v = acc[mi][nj][rg];
        if (RESID) v += res[off];
        C[off] = v;
      }
    }
  }
}

// u[m,e] = silu( conv_b[e] + sum_k conv_w[e,k]*proj_u[b, t+k-3, e] )
__global__ __launch_bounds__(256) void k_conv(const float* __restrict__ proj, const float* __restrict__ cw,
                                              const float* __restrict__ cb, float* __restrict__ u) {
  int m = blockIdx.y;
  int b = m >> 10, t = m & (L_ - 1);
  int e = blockIdx.x * 256 + threadIdx.x;
  float4 w = *(const float4*)(cw + e * 4);
  float wr[4] = {w.x, w.y, w.z, w.w};
  float acc = cb[e];
  #pragma unroll
  for (int k = 0; k < 4; k++) {
    int tt = t + k - 3;
    if (tt >= 0) acc = fmaf(wr[k], proj[(size_t)(b * L_ + tt) * E2_ + e], acc);
  }
  u[(size_t)m * E_ + e] = acc * sigm(acc);
}

// xdbc[m, 0:80] = u[m,:] @ xproj_w[80, E]^T
__global__ __launch_bounds__(256) void k_xproj(const float* __restrict__ u, const float* __restrict__ w,
                                               float* __restrict__ xdbc) {
  __shared__ float us[E_];
  int m = blockIdx.x;
  for (int i = threadIdx.x; i < E_; i += 256) us[i] = u[(size_t)m * E_ + i];
  __syncthreads();
  int wv = threadIdx.x >> 6, ln = threadIdx.x & 63;
  for (int n = wv; n < XD_; n += 4) {
    const float* wr = w + (size_t)n * E_;
    float s = 0.0f;
    for (int k = ln; k < E_; k += 64) s = fmaf(us[k], wr[k], s);
    #pragma unroll
    for (int o = 32; o > 0; o >>= 1) s += __shfl_xor(s, o);
    if (ln == 0) xdbc[(size_t)m * XD_ + n] = s;
  }
}

// dt[m,e] = softplus( xdbc[m,0:48] @ dt_w[e,0:48] + dt_b[e] )
__global__ __launch_bounds__(256) void k_dt(const float* __restrict__ xdbc, const float* __restrict__ dw,
                                            const float* __restrict__ db, float* __restrict__ dt) {
  __shared__ float xs[R_];
  int m = blockIdx.y;
  int e = blockIdx.x * 256 + threadIdx.x;
  if (threadIdx.x < R_) xs[threadIdx.x] = xdbc[(size_t)m * XD_ + threadIdx.x];
  __syncthreads();
  float acc = db[e];
  const float* wr = dw + (size_t)e * R_;
  #pragma unroll
  for (int k = 0; k < R_; k += 4) {
    float4 wv = *(const float4*)(wr + k);
    acc = fmaf(xs[k], wv.x, acc);
    acc = fmaf(xs[k + 1], wv.y, acc);
    acc = fmaf(xs[k + 2], wv.z, acc);
    acc = fmaf(xs[k + 3], wv.w, acc);
  }
  dt[(size_t)m * E_ + e] = softplusf(acc);
}

// Selective scan v2: block = 16e x 16n for one b; T=32 chunked LDS staging,
// register-prefetch double buffer; staging precomputes dt*u, u*D, silu(gate).
// Output y written as bf16 (consumed by out-proj MFMA GEMM).
constexpr int TS_ = 32;
__global__ __launch_bounds__(256) void k_scan2(const float* __restrict__ u, const float* __restrict__ dtb,
                                               const float* __restrict__ xdbc, const float* __restrict__ proj,
                                               const float* __restrict__ A_log, const float* __restrict__ Dp,
                                               ushort* __restrict__ y) {
  __shared__ float s_dt[2][TS_][16];
  __shared__ float s_du[2][TS_][16];
  __shared__ float s_ud[2][TS_][16];
  __shared__ float s_g [2][TS_][16];
  __shared__ float s_bc[2][TS_][32];
  const int tid = threadIdx.x;
  const int e0 = blockIdx.x << 4;
  const int b  = blockIdx.y;
  const int n  = tid & 15, el = tid >> 4;
  const int e  = e0 + el;
  const float A = -__expf(A_log[e * N_ + n]);

  // staging roles
  const int se = tid & 15;   // e within tile
  const int st = tid >> 4;   // t within group of 16
  const float Dv = Dp[e0 + se];

  float r_dt[2], r_u[2], r_g[2], r_bc[4];
  auto issue = [&](int c) {
    int t0 = c * TS_;
    #pragma unroll
    for (int j = 0; j < 2; j++) {
      size_t m = (size_t)(b * L_ + t0 + j * 16 + st);
      r_dt[j] = dtb[m * E_ + e0 + se];
      r_u[j]  = u[m * E_ + e0 + se];
      r_g[j]  = proj[m * E2_ + E_ + e0 + se];
    }
    #pragma unroll
    for (int j = 0; j < 4; j++) {
      int idx = j * 256 + tid;
      r_bc[j] = xdbc[(size_t)(b * L_ + t0 + (idx >> 5)) * XD_ + R_ + (idx & 31)];
    }
  };
  auto commit = [&](int pb) {
    #pragma unroll
    for (int j = 0; j < 2; j++) {
      int t = j * 16 + st;
      s_dt[pb][t][se] = r_dt[j];
      s_du[pb][t][se] = r_dt[j] * r_u[j];
      s_ud[pb][t][se] = r_u[j] * Dv;
      float g = r_g[j];
      s_g[pb][t][se] = g * sigm(g);
    }
    #pragma unroll
    for (int j = 0; j < 4; j++) {
      int idx = j * 256 + tid;
      s_bc[pb][idx >> 5][idx & 31] = r_bc[j];
    }
  };

  issue(0);
  commit(0);
  float hs = 0.0f;
  constexpr int NCH = L_ / TS_;
  for (int c = 0; c < NCH; c++) {
    __syncthreads();
    if (c + 1 < NCH) issue(c + 1);        // global loads in flight during compute
    const int pb = c & 1;
    const int mbase = b * L_ + c * TS_;
    #pragma unroll 4
    for (int t = 0; t < TS_; t++) {
      float dA = __expf(s_dt[pb][t][el] * A);
      float x  = s_du[pb][t][el] * s_bc[pb][t][n];
      hs = fmaf(hs, dA, x);
      float p = hs * s_bc[pb][t][16 + n];
      p += __shfl_xor(p, 1);
      p += __shfl_xor(p, 2);
      p += __shfl_xor(p, 4);
      p += __shfl_xor(p, 8);
      if (n == 0) {
        float yv = (p + s_ud[pb][t][el]) * s_g[pb][t][el];
        y[(size_t)(mbase + t) * E_ + e] = f2b(yv);
      }
    }
    if (c + 1 < NCH) commit((c + 1) & 1);
  }
}

// rs[m] = rsqrt(mean(h[m,:]^2)+eps)
__global__ __launch_bounds__(256) void k_rowscale(const float* __restrict__ h, float* __restrict__ rs) {
  __shared__ float sm[4];
  int m = blockIdx.x, tid = threadIdx.x;
  const float* row = h + (size_t)m * D_;
  float v0 = row[tid], v1 = row[tid + 256], v2 = row[tid + 512];
  float s = block_sum(v0 * v0 + v1 * v1 + v2 * v2, sm);
  if (tid == 0) rs[m] = rsqrtf(s * (1.0f / D_) + EPS_);
}

// pooled[b,d] += fnorm_w[d]/L * sum_t h[b,t,d]*rs[b,t]
__global__ __launch_bounds__(256) void k_pool(const float* __restrict__ h, const float* __restrict__ rs,
                                              const float* __restrict__ fw, float* __restrict__ pooled) {
  int d = blockIdx.x * 256 + threadIdx.x;
  int t0 = blockIdx.y * 128;
  int b = blockIdx.z;
  float acc = 0.0f;
  for (int t = t0; t < t0 + 128; t++) {
    int m = b * L_ + t;
    acc = fmaf(h[(size_t)m * D_ + d], rs[m], acc);
  }
  atomicAdd(&pooled[b * D_ + d], acc * fw[d] * (1.0f / L_));
}

// out[b,c] = pooled[b,:] @ cls_w[c,:] + cls_b[c]
__global__ __launch_bounds__(256) void k_logits(const float* __restrict__ pooled, const float* __restrict__ cw,
                                                const float* __restrict__ cb, float* __restrict__ out) {
  int wv = threadIdx.x >> 6, ln = threadIdx.x & 63;
  for (int p = wv; p < B_ * NC_; p += 4) {
    int b = p / NC_, c = p % NC_;
    float s = 0.0f;
    for (int d = ln; d < D_; d += 64) s = fmaf(pooled[b * D_ + d], cw[c * D_ + d], s);
    #pragma unroll
    for (int o = 32; o > 0; o >>= 1) s += __shfl_xor(s, o);
    if (ln == 0) out[p] = s + cb[c];
  }
}

extern "C" void kernel_launch(void* const* d_in, const int* in_sizes, int n_in,
                              void* d_out, int out_size, void* d_ws, size_t ws_size,
                              hipStream_t stream) {
  const float* x       = (const float*)d_in[0];
  const float* proj_w  = (const float*)d_in[1];
  const float* proj_b  = (const float*)d_in[2];
  const float* norm_w  = (const float*)d_in[3];
  const float* in_w    = (const float*)d_in[4];
  const float* conv_w  = (const float*)d_in[5];
  const float* conv_b  = (const float*)d_in[6];
  const float* xproj_w = (const float*)d_in[7];
  const float* dt_w    = (const float*)d_in[8];
  const float* dt_b    = (const float*)d_in[9];
  const float* A_log   = (const float*)d_in[10];
  const float* D_param = (const float*)d_in[11];
  const float* out_w   = (const float*)d_in[12];
  const float* fnorm_w = (const float*)d_in[13];
  const float* cls_w   = (const float*)d_in[14];
  const float* cls_b   = (const float*)d_in[15];
  float* out = (float*)d_out;

  // workspace layout
  float* h      = (float*)d_ws;                         // M*D
  float* proj   = h + (size_t)M_ * D_;                  // M*2E
  float* ub     = proj + (size_t)M_ * E2_;              // M*E
  float* xdbc   = ub + (size_t)M_ * E_;                 // M*80
  float* dtbuf  = xdbc + (size_t)M_ * XD_;              // M*E
  float* rsb    = dtbuf + (size_t)M_ * E_;              // M
  float* pooled = rsb + M_;                             // B*D
  ushort* hn_bf  = (ushort*)(pooled + B_ * D_);         // M*D bf16
  ushort* y_bf   = hn_bf + (size_t)M_ * D_;             // M*E bf16
  ushort* in_wb  = y_bf + (size_t)M_ * E_;              // E2*D bf16 (per-layer)
  ushort* out_wb = in_wb + (size_t)E2_ * D_;            // D*E bf16 (per-layer)

  k_proj<<<dim3(D_ / 256, M_), 256, 0, stream>>>(x, proj_w, proj_b, h);

  for (int i = 0; i < NL_; i++) {
    // per-layer weight conversion to bf16
    k_f2b<<<(E2_ * D_ / 4 + 255) / 256, 256, 0, stream>>>(in_w + (size_t)i * E2_ * D_, in_wb, E2_ * D_);
    k_f2b<<<(D_ * E_ / 4 + 255) / 256, 256, 0, stream>>>(out_w + (size_t)i * D_ * E_, out_wb, D_ * E_);

    k_rmsnorm_bf<<<M_, 256, 0, stream>>>(h, norm_w + i * D_, hn_bf);
    k_gemm_bf<128, 128, 0><<<dim3(E2_ / 128, M_ / 128), 256, 0, stream>>>(hn_bf, in_wb, proj, nullptr, D_, E2_);
    k_conv<<<dim3(E_ / 256, M_), 256, 0, stream>>>(proj, conv_w + i * E_ * 4, conv_b + i * E_, ub);
    k_xproj<<<M_, 256, 0, stream>>>(ub, xproj_w + (size_t)i * XD_ * E_, xdbc);
    k_dt<<<dim3(E_ / 256, M_), 256, 0, stream>>>(xdbc, dt_w + (size_t)i * E_ * R_, dt_b + i * E_, dtbuf);
    k_scan2<<<dim3(E_ / 16, B_), 256, 0, stream>>>(ub, dtbuf, xdbc, proj,
                                                   A_log + (size_t)i * E_ * N_, D_param + i * E_, y_bf);
    k_gemm_bf<64, 128, 1><<<dim3(D_ / 128, M_ / 64), 256, 0, stream>>>(y_bf, out_wb, h, h, E_, D_);
  }

  k_rowscale<<<M_, 256, 0, stream>>>(h, rsb);
  hipMemsetAsync(pooled, 0, (size_t)B_ * D_ * sizeof(float), stream);
  k_pool<<<dim3(D_ / 256, L_ / 128, B_), 256, 0, stream>>>(h, rsb, fnorm_w, pooled);
  k_logits<<<1, 256, 0, stream>>>(pooled, cls_w, cls_b, out);
}

// Round 3
// 1113.299 us; speedup vs baseline: 3.0689x; 1.8873x over previous
//
#include <hip/hip_runtime.h>

// Problem constants (match reference)
constexpr int B_  = 2;
constexpr int L_  = 1024;
constexpr int D_  = 768;
constexpr int E_  = 1536;
constexpr int N_  = 16;
constexpr int R_  = 48;
constexpr int NL_ = 4;
constexpr int NC_ = 5;
constexpr int M_  = B_ * L_;        // 2048 token rows
constexpr int E2_ = 2 * E_;         // 3072
constexpr int XD_ = R_ + 2 * N_;    // 80
constexpr float EPS_ = 1e-5f;

typedef __attribute__((ext_vector_type(8))) short bf16x8;
typedef __attribute__((ext_vector_type(4))) float f32x4;
typedef const __attribute__((address_space(1))) void* gas_t;
typedef __attribute__((address_space(3))) void* las_t;

__device__ __forceinline__ float sigm(float x) { return 1.0f / (1.0f + __expf(-x)); }
__device__ __forceinline__ float softplusf(float x) { return x > 20.0f ? x : log1pf(__expf(x)); }
__device__ __forceinline__ ushort f2b(float f) {  // fp32 -> bf16 RNE
  union { float f; unsigned u; } v; v.f = f;
  unsigned r = (v.u + 0x7fffu + ((v.u >> 16) & 1u)) >> 16;
  return (ushort)r;
}

// DPP row_ror add: sum over 16-lane rows, full-rate VALU (no ds_swizzle latency)
template <int CTRL>
__device__ __forceinline__ float dpp_add(float x) {
  int yi = __builtin_amdgcn_update_dpp(0, __builtin_bit_cast(int, x), CTRL, 0xf, 0xf, false);
  return x + __builtin_bit_cast(float, yi);
}
__device__ __forceinline__ float row_sum16(float x) {
  x = dpp_add<0x121>(x);  // row_ror:1
  x = dpp_add<0x122>(x);  // row_ror:2
  x = dpp_add<0x124>(x);  // row_ror:4
  x = dpp_add<0x128>(x);  // row_ror:8
  return x;
}

__device__ __forceinline__ float block_sum(float v, float* sm) {
  #pragma unroll
  for (int o = 32; o > 0; o >>= 1) v += __shfl_xor(v, o);
  if ((threadIdx.x & 63) == 0) sm[threadIdx.x >> 6] = v;
  __syncthreads();
  return sm[0] + sm[1] + sm[2] + sm[3];
}

// fp32 -> bf16 bulk convert, n multiple of 4
__global__ __launch_bounds__(256) void k_f2b(const float* __restrict__ s, ushort* __restrict__ d, int nv) {
  int i = (blockIdx.x * 256 + threadIdx.x) * 4;
  if (i >= nv) return;
  float4 v = *(const float4*)(s + i);
  ushort4 o = make_ushort4(f2b(v.x), f2b(v.y), f2b(v.z), f2b(v.w));
  *(ushort4*)(d + i) = o;
}

// dt_w[NL][E][48] -> bf16 padded [NL][E][64] (cols 48..63 = 0)
__global__ __launch_bounds__(256) void k_dtpad(const float* __restrict__ dw, ushort* __restrict__ o) {
  int i = blockIdx.x * 256 + threadIdx.x;           // over NL*E*64
  int k = i & 63, e = i >> 6;
  o[i] = (k < R_) ? f2b(dw[e * R_ + k]) : (ushort)0;
}

// h[m,d] = x[m,:12] @ proj_w[d,:12] + proj_b[d]
__global__ __launch_bounds__(256) void k_proj(const float* __restrict__ x, const float* __restrict__ pw,
                                              const float* __restrict__ pb, float* __restrict__ h) {
  __shared__ float xs[12];
  int m = blockIdx.y;
  int d = blockIdx.x * 256 + threadIdx.x;
  if (threadIdx.x < 12) xs[threadIdx.x] = x[m * 12 + threadIdx.x];
  __syncthreads();
  float acc = pb[d];
  #pragma unroll
  for (int j = 0; j < 12; j++) acc = fmaf(xs[j], pw[d * 12 + j], acc);
  h[(size_t)m * D_ + d] = acc;
}

// hn_bf16[m,:] = rmsnorm(h[m,:]) * w
__global__ __launch_bounds__(256) void k_rmsnorm_bf(const float* __restrict__ h, const float* __restrict__ w,
                                                    ushort* __restrict__ hn) {
  __shared__ float sm[4];
  int m = blockIdx.x, tid = threadIdx.x;
  const float* row = h + (size_t)m * D_;
  float v0 = row[tid], v1 = row[tid + 256], v2 = row[tid + 512];
  float s = block_sum(v0 * v0 + v1 * v1 + v2 * v2, sm);
  float sc = rsqrtf(s * (1.0f / D_) + EPS_);
  ushort* o = hn + (size_t)m * D_;
  o[tid]       = f2b(v0 * sc * w[tid]);
  o[tid + 256] = f2b(v1 * sc * w[tid + 256]);
  o[tid + 512] = f2b(v2 * sc * w[tid + 512]);
}

// C[M,Nd] = A_bf16[M,Kd] @ Bw_bf16[Nd,Kd]^T. MFMA 16x16x32 bf16.
// MODE 0: C=v   MODE 1: C=v+res[off]   MODE 2: C=softplus(v+res[col]) (res=bias)
template <int BM, int BN, int MODE>
__global__ __launch_bounds__(256) void k_gemm_bf(const ushort* __restrict__ A, const ushort* __restrict__ Bw,
                                                 float* __restrict__ C, const float* __restrict__ res,
                                                 int Kd, int Nd) {
  constexpr int AM = BM / 32, BNF = BN / 32;
  __shared__ ushort sA[BM * 32];
  __shared__ ushort sB[BN * 32];
  const int tid = threadIdx.x;
  const int wave = tid >> 6, lane = tid & 63;
  const int q = lane >> 4, r = lane & 15;
  const int wm = wave >> 1, wn = wave & 1;
  const int m0 = blockIdx.y * BM, n0 = blockIdx.x * BN;
  f32x4 acc[AM][BNF] = {};

  for (int k0 = 0; k0 < Kd; k0 += 32) {
    #pragma unroll
    for (int j = 0; j < BM / 64; j++) {
      int i = j * 256 + tid;
      const ushort* gp = A + (size_t)(m0 + (i >> 2)) * Kd + k0 + ((i & 3) << 3);
      __builtin_amdgcn_global_load_lds((gas_t)gp, (las_t)(sA + ((j * 256 + wave * 64) << 3)), 16, 0, 0);
    }
    #pragma unroll
    for (int j = 0; j < BN / 64; j++) {
      int i = j * 256 + tid;
      const ushort* gp = Bw + (size_t)(n0 + (i >> 2)) * Kd + k0 + ((i & 3) << 3);
      __builtin_amdgcn_global_load_lds((gas_t)gp, (las_t)(sB + ((j * 256 + wave * 64) << 3)), 16, 0, 0);
    }
    __syncthreads();
    bf16x8 af[AM], bfv[BNF];
    #pragma unroll
    for (int mi = 0; mi < AM; mi++)
      af[mi] = *(const bf16x8*)&sA[(wm * (BM / 2) + mi * 16 + r) * 32 + q * 8];
    #pragma unroll
    for (int nj = 0; nj < BNF; nj++)
      bfv[nj] = *(const bf16x8*)&sB[(wn * (BN / 2) + nj * 16 + r) * 32 + q * 8];
    #pragma unroll
    for (int mi = 0; mi < AM; mi++)
      #pragma unroll
      for (int nj = 0; nj < BNF; nj++)
        acc[mi][nj] = __builtin_amdgcn_mfma_f32_16x16x32_bf16(af[mi], bfv[nj], acc[mi][nj], 0, 0, 0);
    __syncthreads();
  }
  // C/D layout: col = lane&15, row = (lane>>4)*4 + reg
  #pragma unroll
  for (int mi = 0; mi < AM; mi++) {
    #pragma unroll
    for (int nj = 0; nj < BNF; nj++) {
      int col = n0 + wn * (BN / 2) + nj * 16 + r;
      #pragma unroll
      for (int rg = 0; rg < 4; rg++) {
        int row = m0 + wm * (BM / 2) + mi * 16 + q * 4 + rg;
        size_t off = (size_t)row * Nd + col;
        float v = acc[mi][nj][rg];
        if (MODE == 1) v += res[off];
        if (MODE == 2) v = softplusf(v + res[col]);
        C[off] = v;
      }
    }
  }
}

// xproj GEMM: xdbc[M,80] = u_bf[M,E] @ xwb[80,E]^T.  BM=64, all 80 cols per block.
// Also emits bf16 copy of cols 0..47 zero-padded to 64 (dt GEMM's A operand).
__global__ __launch_bounds__(256) void k_gemm_x(const ushort* __restrict__ A, const ushort* __restrict__ Bw,
                                                float* __restrict__ C, ushort* __restrict__ Cb) {
  __shared__ ushort sA[64 * 32];
  __shared__ ushort sB[80 * 32];
  const int tid = threadIdx.x;
  const int wave = tid >> 6, lane = tid & 63;
  const int q = lane >> 4, r = lane & 15;
  const int m0 = blockIdx.x * 64;
  f32x4 acc[5] = {};

  for (int k0 = 0; k0 < E_; k0 += 32) {
    {
      const ushort* gp = A + (size_t)(m0 + wave * 16 + (lane >> 2)) * E_ + k0 + ((lane & 3) << 3);
      __builtin_amdgcn_global_load_lds((gas_t)gp, (las_t)(sA + (wave << 9)), 16, 0, 0);
    }
    #pragma unroll
    for (int j = wave; j < 5; j += 4) {
      const ushort* gp = Bw + (size_t)(j * 16 + (lane >> 2)) * E_ + k0 + ((lane & 3) << 3);
      __builtin_amdgcn_global_load_lds((gas_t)gp, (las_t)(sB + (j << 9)), 16, 0, 0);
    }
    __syncthreads();
    bf16x8 af = *(const bf16x8*)&sA[(wave * 16 + r) * 32 + q * 8];
    #pragma unroll
    for (int nj = 0; nj < 5; nj++) {
      bf16x8 bfv = *(const bf16x8*)&sB[(nj * 16 + r) * 32 + q * 8];
      acc[nj] = __builtin_amdgcn_mfma_f32_16x16x32_bf16(af, bfv, acc[nj], 0, 0, 0);
    }
    __syncthreads();
  }
  #pragma unroll
  for (int nj = 0; nj < 5; nj++) {
    int col = nj * 16 + r;
    #pragma unroll
    for (int rg = 0; rg < 4; rg++) {
      int row = m0 + wave * 16 + q * 4 + rg;
      float v = acc[nj][rg];
      C[(size_t)row * XD_ + col] = v;
      if (col < R_) Cb[(size_t)row * 64 + col] = f2b(v);
      else if (col < 64) Cb[(size_t)row * 64 + col] = 0;
    }
  }
}

// u[m,e] = silu( conv_b[e] + sum_k conv_w[e,k]*proj_u[b, t+k-3, e] ); also bf16 copy
__global__ __launch_bounds__(256) void k_conv(const float* __restrict__ proj, const float* __restrict__ cw,
                                              const float* __restrict__ cb, float* __restrict__ u,
                                              ushort* __restrict__ ub16) {
  int m = blockIdx.y;
  int b = m >> 10, t = m & (L_ - 1);
  int e = blockIdx.x * 256 + threadIdx.x;
  float4 w = *(const float4*)(cw + e * 4);
  float wr[4] = {w.x, w.y, w.z, w.w};
  float acc = cb[e];
  #pragma unroll
  for (int k = 0; k < 4; k++) {
    int tt = t + k - 3;
    if (tt >= 0) acc = fmaf(wr[k], proj[(size_t)(b * L_ + tt) * E2_ + e], acc);
  }
  float uv = acc * sigm(acc);
  u[(size_t)m * E_ + e] = uv;
  ub16[(size_t)m * E_ + e] = f2b(uv);
}

// Selective scan v3: block = 16e x 16n; chunked LDS staging (float2-packed),
// register double-buffer prefetch, DPP row-sum reduce (no ds_swizzle on hot path).
constexpr int TS_ = 32;
__global__ __launch_bounds__(256) void k_scan3(const float* __restrict__ u, const float* __restrict__ dtb,
                                               const float* __restrict__ xdbc, const float* __restrict__ proj,
                                               const float* __restrict__ A_log, const float* __restrict__ Dp,
                                               ushort* __restrict__ y) {
  __shared__ float2 s_dtu[2][TS_][16];   // (dt, dt*u)
  __shared__ float2 s_bc [2][TS_][16];   // (B_n, C_n)
  __shared__ float2 s_og [2][TS_][16];   // (u*D, silu(gate))
  const int tid = threadIdx.x;
  const int e0 = blockIdx.x << 4;
  const int b  = blockIdx.y;
  const int n  = tid & 15, el = tid >> 4;
  const int e  = e0 + el;
  const float A = -__expf(A_log[e * N_ + n]);

  const int se = tid & 15;   // staging e
  const int st = tid >> 4;   // staging t (0..15)
  const float Dv = Dp[e0 + se];

  float r_dt[2], r_u[2], r_g[2], r_bc[4];
  auto issue = [&](int c) {
    int t0 = c * TS_;
    #pragma unroll
    for (int j = 0; j < 2; j++) {
      size_t m = (size_t)(b * L_ + t0 + j * 16 + st);
      r_dt[j] = dtb[m * E_ + e0 + se];
      r_u[j]  = u[m * E_ + e0 + se];
      r_g[j]  = proj[m * E2_ + E_ + e0 + se];
    }
    #pragma unroll
    for (int j = 0; j < 4; j++) {
      int idx = j * 256 + tid;
      r_bc[j] = xdbc[(size_t)(b * L_ + t0 + (idx >> 5)) * XD_ + R_ + (idx & 31)];
    }
  };
  auto commit = [&](int pb) {
    #pragma unroll
    for (int j = 0; j < 2; j++) {
      int t = j * 16 + st;
      s_dtu[pb][t][se] = make_float2(r_dt[j], r_dt[j] * r_u[j]);
      float g = r_g[j];
      s_og[pb][t][se] = make_float2(r_u[j] * Dv, g * sigm(g));
    }
    #pragma unroll
    for (int j = 0; j < 4; j++) {
      int idx = j * 256 + tid;
      int t = idx >> 5, col = idx & 31;
      ((float*)&s_bc[pb][t][0])[((col & 15) << 1) + (col >> 4)] = r_bc[j];
    }
  };

  issue(0);
  commit(0);
  float hs = 0.0f;
  constexpr int NCH = L_ / TS_;
  for (int c = 0; c < NCH; c++) {
    __syncthreads();
    if (c + 1 < NCH) issue(c + 1);        // global loads in flight during compute
    const int pb = c & 1;
    const int mbase = b * L_ + c * TS_;
    #pragma unroll
    for (int t = 0; t < TS_; t++) {
      float2 dtu = s_dtu[pb][t][el];
      float2 bc  = s_bc[pb][t][n];
      float dA = __expf(dtu.x * A);
      hs = fmaf(hs, dA, dtu.y * bc.x);
      float p = row_sum16(hs * bc.y);
      if (n == 0) {
        float2 og = s_og[pb][t][el];
        y[(size_t)(mbase + t) * E_ + e] = f2b((p + og.x) * og.y);
      }
    }
    if (c + 1 < NCH) commit((c + 1) & 1);
  }
}

// rs[m] = rsqrt(mean(h[m,:]^2)+eps)
__global__ __launch_bounds__(256) void k_rowscale(const float* __restrict__ h, float* __restrict__ rs) {
  __shared__ float sm[4];
  int m = blockIdx.x, tid = threadIdx.x;
  const float* row = h + (size_t)m * D_;
  float v0 = row[tid], v1 = row[tid + 256], v2 = row[tid + 512];
  float s = block_sum(v0 * v0 + v1 * v1 + v2 * v2, sm);
  if (tid == 0) rs[m] = rsqrtf(s * (1.0f / D_) + EPS_);
}

// pooled[b,d] += fnorm_w[d]/L * sum_t h[b,t,d]*rs[b,t]
__global__ __launch_bounds__(256) void k_pool(const float* __restrict__ h, const float* __restrict__ rs,
                                              const float* __restrict__ fw, float* __restrict__ pooled) {
  int d = blockIdx.x * 256 + threadIdx.x;
  int t0 = blockIdx.y * 128;
  int b = blockIdx.z;
  float acc = 0.0f;
  for (int t = t0; t < t0 + 128; t++) {
    int m = b * L_ + t;
    acc = fmaf(h[(size_t)m * D_ + d], rs[m], acc);
  }
  atomicAdd(&pooled[b * D_ + d], acc * fw[d] * (1.0f / L_));
}

// out[b,c] = pooled[b,:] @ cls_w[c,:] + cls_b[c]
__global__ __launch_bounds__(256) void k_logits(const float* __restrict__ pooled, const float* __restrict__ cw,
                                                const float* __restrict__ cb, float* __restrict__ out) {
  int wv = threadIdx.x >> 6, ln = threadIdx.x & 63;
  for (int p = wv; p < B_ * NC_; p += 4) {
    int b = p / NC_, c = p % NC_;
    float s = 0.0f;
    for (int d = ln; d < D_; d += 64) s = fmaf(pooled[b * D_ + d], cw[c * D_ + d], s);
    #pragma unroll
    for (int o = 32; o > 0; o >>= 1) s += __shfl_xor(s, o);
    if (ln == 0) out[p] = s + cb[c];
  }
}

extern "C" void kernel_launch(void* const* d_in, const int* in_sizes, int n_in,
                              void* d_out, int out_size, void* d_ws, size_t ws_size,
                              hipStream_t stream) {
  const float* x       = (const float*)d_in[0];
  const float* proj_w  = (const float*)d_in[1];
  const float* proj_b  = (const float*)d_in[2];
  const float* norm_w  = (const float*)d_in[3];
  const float* in_w    = (const float*)d_in[4];
  const float* conv_w  = (const float*)d_in[5];
  const float* conv_b  = (const float*)d_in[6];
  const float* xproj_w = (const float*)d_in[7];
  const float* dt_w    = (const float*)d_in[8];
  const float* dt_b    = (const float*)d_in[9];
  const float* A_log   = (const float*)d_in[10];
  const float* D_param = (const float*)d_in[11];
  const float* out_w   = (const float*)d_in[12];
  const float* fnorm_w = (const float*)d_in[13];
  const float* cls_w   = (const float*)d_in[14];
  const float* cls_b   = (const float*)d_in[15];
  float* out = (float*)d_out;

  // workspace layout
  float* h      = (float*)d_ws;                         // M*D
  float* proj   = h + (size_t)M_ * D_;                  // M*2E
  float* ub     = proj + (size_t)M_ * E2_;              // M*E
  float* xdbc   = ub + (size_t)M_ * E_;                 // M*80
  float* dtbuf  = xdbc + (size_t)M_ * XD_;              // M*E
  float* rsb    = dtbuf + (size_t)M_ * E_;              // M
  float* pooled = rsb + M_;                             // B*D
  ushort* hn_bf   = (ushort*)(pooled + B_ * D_);        // M*D
  ushort* y_bf    = hn_bf + (size_t)M_ * D_;            // M*E
  ushort* ub_bf   = y_bf + (size_t)M_ * E_;             // M*E
  ushort* xdbc_bf = ub_bf + (size_t)M_ * E_;            // M*64
  ushort* xwb     = xdbc_bf + (size_t)M_ * 64;          // NL*80*E
  ushort* dtwb    = xwb + (size_t)NL_ * XD_ * E_;       // NL*E*64
  ushort* in_wb   = dtwb + (size_t)NL_ * E_ * 64;       // E2*D (per-layer)
  ushort* out_wb  = in_wb + (size_t)E2_ * D_;           // D*E (per-layer)

  // one-time weight conversions (small)
  k_f2b<<<(NL_ * XD_ * E_ / 4 + 255) / 256, 256, 0, stream>>>(xproj_w, xwb, NL_ * XD_ * E_);
  k_dtpad<<<NL_ * E_ * 64 / 256, 256, 0, stream>>>(dt_w, dtwb);

  k_proj<<<dim3(D_ / 256, M_), 256, 0, stream>>>(x, proj_w, proj_b, h);

  for (int i = 0; i < NL_; i++) {
    k_f2b<<<(E2_ * D_ / 4 + 255) / 256, 256, 0, stream>>>(in_w + (size_t)i * E2_ * D_, in_wb, E2_ * D_);
    k_f2b<<<(D_ * E_ / 4 + 255) / 256, 256, 0, stream>>>(out_w + (size_t)i * D_ * E_, out_wb, D_ * E_);

    k_rmsnorm_bf<<<M_, 256, 0, stream>>>(h, norm_w + i * D_, hn_bf);
    k_gemm_bf<128, 128, 0><<<dim3(E2_ / 128, M_ / 128), 256, 0, stream>>>(hn_bf, in_wb, proj, nullptr, D_, E2_);
    k_conv<<<dim3(E_ / 256, M_), 256, 0, stream>>>(proj, conv_w + i * E_ * 4, conv_b + i * E_, ub, ub_bf);
    k_gemm_x<<<M_ / 64, 256, 0, stream>>>(ub_bf, xwb + (size_t)i * XD_ * E_, xdbc, xdbc_bf);
    k_gemm_bf<64, 128, 2><<<dim3(E_ / 128, M_ / 64), 256, 0, stream>>>(xdbc_bf, dtwb + (size_t)i * E_ * 64,
                                                                       dtbuf, dt_b + i * E_, 64, E_);
    k_scan3<<<dim3(E_ / 16, B_), 256, 0, stream>>>(ub, dtbuf, xdbc, proj,
                                                   A_log + (size_t)i * E_ * N_, D_param + i * E_, y_bf);
    k_gemm_bf<64, 128, 1><<<dim3(D_ / 128, M_ / 64), 256, 0, stream>>>(y_bf, out_wb, h, h, E_, D_);
  }

  k_rowscale<<<M_, 256, 0, stream>>>(h, rsb);
  hipMemsetAsync(pooled, 0, (size_t)B_ * D_ * sizeof(float), stream);
  k_pool<<<dim3(D_ / 256, L_ / 128, B_), 256, 0, stream>>>(h, rsb, fnorm_w, pooled);
  k_logits<<<1, 256, 0, stream>>>(pooled, cls_w, cls_b, out);
}

// Round 4
// 823.621 us; speedup vs baseline: 4.1482x; 1.3517x over previous
//
#include <hip/hip_runtime.h>

// Problem constants (match reference)
constexpr int B_  = 2;
constexpr int L_  = 1024;
constexpr int D_  = 768;
constexpr int E_  = 1536;
constexpr int N_  = 16;
constexpr int R_  = 48;
constexpr int NL_ = 4;
constexpr int NC_ = 5;
constexpr int M_  = B_ * L_;        // 2048 token rows
constexpr int E2_ = 2 * E_;         // 3072
constexpr int XD_ = R_ + 2 * N_;    // 80
constexpr float EPS_ = 1e-5f;

constexpr int NCH_ = 8;             // time-chunks for parallel scan
constexpr int CL_  = L_ / NCH_;     // 128 timesteps per chunk
constexpr int TS_  = 32;            // LDS staging sub-chunk

typedef __attribute__((ext_vector_type(8))) short bf16x8;
typedef __attribute__((ext_vector_type(4))) float f32x4;
typedef const __attribute__((address_space(1))) void* gas_t;
typedef __attribute__((address_space(3))) void* las_t;

__device__ __forceinline__ float sigm(float x) { return 1.0f / (1.0f + __expf(-x)); }
__device__ __forceinline__ float softplusf(float x) { return x > 20.0f ? x : log1pf(__expf(x)); }
__device__ __forceinline__ ushort f2b(float f) {  // fp32 -> bf16 RNE
  union { float f; unsigned u; } v; v.f = f;
  unsigned r = (v.u + 0x7fffu + ((v.u >> 16) & 1u)) >> 16;
  return (ushort)r;
}

// DPP row_ror add: sum over 16-lane rows, full-rate VALU
template <int CTRL>
__device__ __forceinline__ float dpp_add(float x) {
  int yi = __builtin_amdgcn_update_dpp(0, __builtin_bit_cast(int, x), CTRL, 0xf, 0xf, false);
  return x + __builtin_bit_cast(float, yi);
}
__device__ __forceinline__ float row_sum16(float x) {
  x = dpp_add<0x121>(x);
  x = dpp_add<0x122>(x);
  x = dpp_add<0x124>(x);
  x = dpp_add<0x128>(x);
  return x;
}

__device__ __forceinline__ float block_sum(float v, float* sm) {
  #pragma unroll
  for (int o = 32; o > 0; o >>= 1) v += __shfl_xor(v, o);
  if ((threadIdx.x & 63) == 0) sm[threadIdx.x >> 6] = v;
  __syncthreads();
  return sm[0] + sm[1] + sm[2] + sm[3];
}

// fp32 -> bf16 bulk convert, n multiple of 4
__global__ __launch_bounds__(256) void k_f2b(const float* __restrict__ s, ushort* __restrict__ d, int nv) {
  int i = (blockIdx.x * 256 + threadIdx.x) * 4;
  if (i >= nv) return;
  float4 v = *(const float4*)(s + i);
  ushort4 o = make_ushort4(f2b(v.x), f2b(v.y), f2b(v.z), f2b(v.w));
  *(ushort4*)(d + i) = o;
}

// dt_w[NL][E][48] -> bf16 padded [NL][E][64]
__global__ __launch_bounds__(256) void k_dtpad(const float* __restrict__ dw, ushort* __restrict__ o) {
  int i = blockIdx.x * 256 + threadIdx.x;
  int k = i & 63, e = i >> 6;
  o[i] = (k < R_) ? f2b(dw[e * R_ + k]) : (ushort)0;
}

// h[m,d] = x[m,:12] @ proj_w[d,:12] + proj_b[d]
__global__ __launch_bounds__(256) void k_proj(const float* __restrict__ x, const float* __restrict__ pw,
                                              const float* __restrict__ pb, float* __restrict__ h) {
  __shared__ float xs[12];
  int m = blockIdx.y;
  int d = blockIdx.x * 256 + threadIdx.x;
  if (threadIdx.x < 12) xs[threadIdx.x] = x[m * 12 + threadIdx.x];
  __syncthreads();
  float acc = pb[d];
  #pragma unroll
  for (int j = 0; j < 12; j++) acc = fmaf(xs[j], pw[d * 12 + j], acc);
  h[(size_t)m * D_ + d] = acc;
}

// hn_bf16[m,:] = rmsnorm(h[m,:]) * w
__global__ __launch_bounds__(256) void k_rmsnorm_bf(const float* __restrict__ h, const float* __restrict__ w,
                                                    ushort* __restrict__ hn) {
  __shared__ float sm[4];
  int m = blockIdx.x, tid = threadIdx.x;
  const float* row = h + (size_t)m * D_;
  float v0 = row[tid], v1 = row[tid + 256], v2 = row[tid + 512];
  float s = block_sum(v0 * v0 + v1 * v1 + v2 * v2, sm);
  float sc = rsqrtf(s * (1.0f / D_) + EPS_);
  ushort* o = hn + (size_t)m * D_;
  o[tid]       = f2b(v0 * sc * w[tid]);
  o[tid + 256] = f2b(v1 * sc * w[tid + 256]);
  o[tid + 512] = f2b(v2 * sc * w[tid + 512]);
}

// C[M,Nd] = A_bf16[M,Kd] @ Bw_bf16[Nd,Kd]^T. MFMA 16x16x32 bf16.
// MODE 0: C=v   MODE 1: C=v+res[off]   MODE 2: C=softplus(v+res[col]) (res=bias)
template <int BM, int BN, int MODE>
__global__ __launch_bounds__(256) void k_gemm_bf(const ushort* __restrict__ A, const ushort* __restrict__ Bw,
                                                 float* __restrict__ C, const float* __restrict__ res,
                                                 int Kd, int Nd) {
  constexpr int AM = BM / 32, BNF = BN / 32;
  __shared__ ushort sA[BM * 32];
  __shared__ ushort sB[BN * 32];
  const int tid = threadIdx.x;
  const int wave = tid >> 6, lane = tid & 63;
  const int q = lane >> 4, r = lane & 15;
  const int wm = wave >> 1, wn = wave & 1;
  const int m0 = blockIdx.y * BM, n0 = blockIdx.x * BN;
  f32x4 acc[AM][BNF] = {};

  for (int k0 = 0; k0 < Kd; k0 += 32) {
    #pragma unroll
    for (int j = 0; j < BM / 64; j++) {
      int i = j * 256 + tid;
      const ushort* gp = A + (size_t)(m0 + (i >> 2)) * Kd + k0 + ((i & 3) << 3);
      __builtin_amdgcn_global_load_lds((gas_t)gp, (las_t)(sA + ((j * 256 + wave * 64) << 3)), 16, 0, 0);
    }
    #pragma unroll
    for (int j = 0; j < BN / 64; j++) {
      int i = j * 256 + tid;
      const ushort* gp = Bw + (size_t)(n0 + (i >> 2)) * Kd + k0 + ((i & 3) << 3);
      __builtin_amdgcn_global_load_lds((gas_t)gp, (las_t)(sB + ((j * 256 + wave * 64) << 3)), 16, 0, 0);
    }
    __syncthreads();
    bf16x8 af[AM], bfv[BNF];
    #pragma unroll
    for (int mi = 0; mi < AM; mi++)
      af[mi] = *(const bf16x8*)&sA[(wm * (BM / 2) + mi * 16 + r) * 32 + q * 8];
    #pragma unroll
    for (int nj = 0; nj < BNF; nj++)
      bfv[nj] = *(const bf16x8*)&sB[(wn * (BN / 2) + nj * 16 + r) * 32 + q * 8];
    #pragma unroll
    for (int mi = 0; mi < AM; mi++)
      #pragma unroll
      for (int nj = 0; nj < BNF; nj++)
        acc[mi][nj] = __builtin_amdgcn_mfma_f32_16x16x32_bf16(af[mi], bfv[nj], acc[mi][nj], 0, 0, 0);
    __syncthreads();
  }
  #pragma unroll
  for (int mi = 0; mi < AM; mi++) {
    #pragma unroll
    for (int nj = 0; nj < BNF; nj++) {
      int col = n0 + wn * (BN / 2) + nj * 16 + r;
      #pragma unroll
      for (int rg = 0; rg < 4; rg++) {
        int row = m0 + wm * (BM / 2) + mi * 16 + q * 4 + rg;
        size_t off = (size_t)row * Nd + col;
        float v = acc[mi][nj][rg];
        if (MODE == 1) v += res[off];
        if (MODE == 2) v = softplusf(v + res[col]);
        C[off] = v;
      }
    }
  }
}

// xproj GEMM: xdbc[M,80] = u_bf[M,E] @ xwb[80,E]^T; also bf16 copy of cols 0..47 pad 64
__global__ __launch_bounds__(256) void k_gemm_x(const ushort* __restrict__ A, const ushort* __restrict__ Bw,
                                                float* __restrict__ C, ushort* __restrict__ Cb) {
  __shared__ ushort sA[64 * 32];
  __shared__ ushort sB[80 * 32];
  const int tid = threadIdx.x;
  const int wave = tid >> 6, lane = tid & 63;
  const int q = lane >> 4, r = lane & 15;
  const int m0 = blockIdx.x * 64;
  f32x4 acc[5] = {};

  for (int k0 = 0; k0 < E_; k0 += 32) {
    {
      const ushort* gp = A + (size_t)(m0 + wave * 16 + (lane >> 2)) * E_ + k0 + ((lane & 3) << 3);
      __builtin_amdgcn_global_load_lds((gas_t)gp, (las_t)(sA + (wave << 9)), 16, 0, 0);
    }
    #pragma unroll
    for (int j = wave; j < 5; j += 4) {
      const ushort* gp = Bw + (size_t)(j * 16 + (lane >> 2)) * E_ + k0 + ((lane & 3) << 3);
      __builtin_amdgcn_global_load_lds((gas_t)gp, (las_t)(sB + (j << 9)), 16, 0, 0);
    }
    __syncthreads();
    bf16x8 af = *(const bf16x8*)&sA[(wave * 16 + r) * 32 + q * 8];
    #pragma unroll
    for (int nj = 0; nj < 5; nj++) {
      bf16x8 bfv = *(const bf16x8*)&sB[(nj * 16 + r) * 32 + q * 8];
      acc[nj] = __builtin_amdgcn_mfma_f32_16x16x32_bf16(af, bfv, acc[nj], 0, 0, 0);
    }
    __syncthreads();
  }
  #pragma unroll
  for (int nj = 0; nj < 5; nj++) {
    int col = nj * 16 + r;
    #pragma unroll
    for (int rg = 0; rg < 4; rg++) {
      int row = m0 + wave * 16 + q * 4 + rg;
      float v = acc[nj][rg];
      C[(size_t)row * XD_ + col] = v;
      if (col < R_) Cb[(size_t)row * 64 + col] = f2b(v);
      else if (col < 64) Cb[(size_t)row * 64 + col] = 0;
    }
  }
}

// u[m,e] = silu(conv...); also bf16 copy
__global__ __launch_bounds__(256) void k_conv(const float* __restrict__ proj, const float* __restrict__ cw,
                                              const float* __restrict__ cb, float* __restrict__ u,
                                              ushort* __restrict__ ub16) {
  int m = blockIdx.y;
  int b = m >> 10, t = m & (L_ - 1);
  int e = blockIdx.x * 256 + threadIdx.x;
  float4 w = *(const float4*)(cw + e * 4);
  float wr[4] = {w.x, w.y, w.z, w.w};
  float acc = cb[e];
  #pragma unroll
  for (int k = 0; k < 4; k++) {
    int tt = t + k - 3;
    if (tt >= 0) acc = fmaf(wr[k], proj[(size_t)(b * L_ + tt) * E2_ + e], acc);
  }
  float uv = acc * sigm(acc);
  u[(size_t)m * E_ + e] = uv;
  ub16[(size_t)m * E_ + e] = f2b(uv);
}

// ---- Parallel (chunked) selective scan --------------------------------------
// h_t = dA_t*h_{t-1} + dt_t*u_t*B_t  is elementwise-diagonal => chunk-parallel.
// Phase A: per (e-tile, b, chunk): local scan from h=0 -> P=prod(dA), S=h_end.
// Phase B: per (b,e,n): h_in[c] = sequential combine of 8 chunk summaries.
// Phase C: per chunk re-scan seeded with h_in, emit y.

__global__ __launch_bounds__(256) void k_scanA(const float* __restrict__ u, const float* __restrict__ dtb,
                                               const float* __restrict__ xdbc, const float* __restrict__ A_log,
                                               float* __restrict__ Pst, float* __restrict__ Sst) {
  __shared__ float2 s_dtu[2][TS_][16];   // (dt, dt*u)
  __shared__ float  s_b [2][TS_][16];    // B_n
  const int tid = threadIdx.x;
  const int e0 = blockIdx.x << 4;
  const int b  = blockIdx.y;
  const int c  = blockIdx.z;
  const int n  = tid & 15, el = tid >> 4;
  const int e  = e0 + el;
  const float A = -__expf(A_log[e * N_ + n]);
  const int se = tid & 15, st = tid >> 4;

  float r_dt[2], r_u[2], r_b[2];
  auto issue = [&](int s) {
    int t0 = c * CL_ + s * TS_;
    #pragma unroll
    for (int j = 0; j < 2; j++) {
      size_t m = (size_t)(b * L_ + t0 + j * 16 + st);
      r_dt[j] = dtb[m * E_ + e0 + se];
      r_u[j]  = u[m * E_ + e0 + se];
    }
    #pragma unroll
    for (int j = 0; j < 2; j++) {
      int idx = j * 256 + tid;
      r_b[j] = xdbc[(size_t)(b * L_ + t0 + (idx >> 4)) * XD_ + R_ + (idx & 15)];
    }
  };
  auto commit = [&](int pb) {
    #pragma unroll
    for (int j = 0; j < 2; j++) {
      int t = j * 16 + st;
      s_dtu[pb][t][se] = make_float2(r_dt[j], r_dt[j] * r_u[j]);
    }
    #pragma unroll
    for (int j = 0; j < 2; j++) {
      int idx = j * 256 + tid;
      s_b[pb][idx >> 4][idx & 15] = r_b[j];
    }
  };

  issue(0);
  commit(0);
  float hs = 0.0f, pp = 1.0f;
  constexpr int NS = CL_ / TS_;
  for (int s = 0; s < NS; s++) {
    __syncthreads();
    if (s + 1 < NS) issue(s + 1);
    const int pb = s & 1;
    #pragma unroll
    for (int t = 0; t < TS_; t++) {
      float2 dtu = s_dtu[pb][t][el];
      float bv   = s_b[pb][t][n];
      float dA = __expf(dtu.x * A);
      hs = fmaf(hs, dA, dtu.y * bv);
      pp *= dA;
    }
    if (s + 1 < NS) commit((s + 1) & 1);
  }
  size_t o = (((size_t)(b * NCH_ + c) * E_) + e) * N_ + n;
  Pst[o] = pp;
  Sst[o] = hs;
}

__global__ __launch_bounds__(256) void k_scanB(const float* __restrict__ Pst, const float* __restrict__ Sst,
                                               float* __restrict__ Hin) {
  int idx = blockIdx.x * 256 + threadIdx.x;       // over B*E*N
  int b = idx / (E_ * N_);
  int en = idx - b * (E_ * N_);
  float h = 0.0f;
  #pragma unroll
  for (int c = 0; c < NCH_; c++) {
    size_t o = (size_t)(b * NCH_ + c) * (E_ * N_) + en;
    Hin[o] = h;
    h = fmaf(Pst[o], h, Sst[o]);
  }
}

__global__ __launch_bounds__(256) void k_scanC(const float* __restrict__ u, const float* __restrict__ dtb,
                                               const float* __restrict__ xdbc, const float* __restrict__ proj,
                                               const float* __restrict__ A_log, const float* __restrict__ Dp,
                                               const float* __restrict__ Hin, ushort* __restrict__ y) {
  __shared__ float2 s_dtu[2][TS_][16];   // (dt, dt*u)
  __shared__ float2 s_bc [2][TS_][16];   // (B_n, C_n)
  __shared__ float2 s_og [2][TS_][16];   // (u*D, silu(gate))
  const int tid = threadIdx.x;
  const int e0 = blockIdx.x << 4;
  const int b  = blockIdx.y;
  const int c  = blockIdx.z;
  const int n  = tid & 15, el = tid >> 4;
  const int e  = e0 + el;
  const float A = -__expf(A_log[e * N_ + n]);
  const int se = tid & 15, st = tid >> 4;
  const float Dv = Dp[e0 + se];

  float r_dt[2], r_u[2], r_g[2], r_bc[4];
  auto issue = [&](int s) {
    int t0 = c * CL_ + s * TS_;
    #pragma unroll
    for (int j = 0; j < 2; j++) {
      size_t m = (size_t)(b * L_ + t0 + j * 16 + st);
      r_dt[j] = dtb[m * E_ + e0 + se];
      r_u[j]  = u[m * E_ + e0 + se];
      r_g[j]  = proj[m * E2_ + E_ + e0 + se];
    }
    #pragma unroll
    for (int j = 0; j < 4; j++) {
      int idx = j * 256 + tid;
      r_bc[j] = xdbc[(size_t)(b * L_ + t0 + (idx >> 5)) * XD_ + R_ + (idx & 31)];
    }
  };
  auto commit = [&](int pb) {
    #pragma unroll
    for (int j = 0; j < 2; j++) {
      int t = j * 16 + st;
      s_dtu[pb][t][se] = make_float2(r_dt[j], r_dt[j] * r_u[j]);
      float g = r_g[j];
      s_og[pb][t][se] = make_float2(r_u[j] * Dv, g * sigm(g));
    }
    #pragma unroll
    for (int j = 0; j < 4; j++) {
      int idx = j * 256 + tid;
      int t = idx >> 5, col = idx & 31;
      ((float*)&s_bc[pb][t][0])[((col & 15) << 1) + (col >> 4)] = r_bc[j];
    }
  };

  issue(0);
  commit(0);
  float hs = Hin[(((size_t)(b * NCH_ + c) * E_) + e) * N_ + n];
  constexpr int NS = CL_ / TS_;
  for (int s = 0; s < NS; s++) {
    __syncthreads();
    if (s + 1 < NS) issue(s + 1);
    const int pb = s & 1;
    const int mbase = b * L_ + c * CL_ + s * TS_;
    #pragma unroll
    for (int t = 0; t < TS_; t++) {
      float2 dtu = s_dtu[pb][t][el];
      float2 bc  = s_bc[pb][t][n];
      float dA = __expf(dtu.x * A);
      hs = fmaf(hs, dA, dtu.y * bc.x);
      float p = row_sum16(hs * bc.y);
      if (n == 0) {
        float2 og = s_og[pb][t][el];
        y[(size_t)(mbase + t) * E_ + e] = f2b((p + og.x) * og.y);
      }
    }
    if (s + 1 < NS) commit((s + 1) & 1);
  }
}

// rs[m] = rsqrt(mean(h[m,:]^2)+eps)
__global__ __launch_bounds__(256) void k_rowscale(const float* __restrict__ h, float* __restrict__ rs) {
  __shared__ float sm[4];
  int m = blockIdx.x, tid = threadIdx.x;
  const float* row = h + (size_t)m * D_;
  float v0 = row[tid], v1 = row[tid + 256], v2 = row[tid + 512];
  float s = block_sum(v0 * v0 + v1 * v1 + v2 * v2, sm);
  if (tid == 0) rs[m] = rsqrtf(s * (1.0f / D_) + EPS_);
}

// pooled[b,d] += fnorm_w[d]/L * sum_t h[b,t,d]*rs[b,t]
__global__ __launch_bounds__(256) void k_pool(const float* __restrict__ h, const float* __restrict__ rs,
                                              const float* __restrict__ fw, float* __restrict__ pooled) {
  int d = blockIdx.x * 256 + threadIdx.x;
  int t0 = blockIdx.y * 128;
  int b = blockIdx.z;
  float acc = 0.0f;
  for (int t = t0; t < t0 + 128; t++) {
    int m = b * L_ + t;
    acc = fmaf(h[(size_t)m * D_ + d], rs[m], acc);
  }
  atomicAdd(&pooled[b * D_ + d], acc * fw[d] * (1.0f / L_));
}

// out[b,c] = pooled[b,:] @ cls_w[c,:] + cls_b[c]
__global__ __launch_bounds__(256) void k_logits(const float* __restrict__ pooled, const float* __restrict__ cw,
                                                const float* __restrict__ cb, float* __restrict__ out) {
  int wv = threadIdx.x >> 6, ln = threadIdx.x & 63;
  for (int p = wv; p < B_ * NC_; p += 4) {
    int b = p / NC_, c = p % NC_;
    float s = 0.0f;
    for (int d = ln; d < D_; d += 64) s = fmaf(pooled[b * D_ + d], cw[c * D_ + d], s);
    #pragma unroll
    for (int o = 32; o > 0; o >>= 1) s += __shfl_xor(s, o);
    if (ln == 0) out[p] = s + cb[c];
  }
}

extern "C" void kernel_launch(void* const* d_in, const int* in_sizes, int n_in,
                              void* d_out, int out_size, void* d_ws, size_t ws_size,
                              hipStream_t stream) {
  const float* x       = (const float*)d_in[0];
  const float* proj_w  = (const float*)d_in[1];
  const float* proj_b  = (const float*)d_in[2];
  const float* norm_w  = (const float*)d_in[3];
  const float* in_w    = (const float*)d_in[4];
  const float* conv_w  = (const float*)d_in[5];
  const float* conv_b  = (const float*)d_in[6];
  const float* xproj_w = (const float*)d_in[7];
  const float* dt_w    = (const float*)d_in[8];
  const float* dt_b    = (const float*)d_in[9];
  const float* A_log   = (const float*)d_in[10];
  const float* D_param = (const float*)d_in[11];
  const float* out_w   = (const float*)d_in[12];
  const float* fnorm_w = (const float*)d_in[13];
  const float* cls_w   = (const float*)d_in[14];
  const float* cls_b   = (const float*)d_in[15];
  float* out = (float*)d_out;

  // workspace layout
  float* h      = (float*)d_ws;                         // M*D
  float* proj   = h + (size_t)M_ * D_;                  // M*2E
  float* ub     = proj + (size_t)M_ * E2_;              // M*E
  float* xdbc   = ub + (size_t)M_ * E_;                 // M*80
  float* dtbuf  = xdbc + (size_t)M_ * XD_;              // M*E
  float* rsb    = dtbuf + (size_t)M_ * E_;              // M
  float* pooled = rsb + M_;                             // B*D
  float* Pst    = pooled + B_ * D_;                     // B*NCH*E*N
  float* Sst    = Pst + (size_t)B_ * NCH_ * E_ * N_;    // B*NCH*E*N
  float* Hin    = Sst + (size_t)B_ * NCH_ * E_ * N_;    // B*NCH*E*N
  ushort* hn_bf   = (ushort*)(Hin + (size_t)B_ * NCH_ * E_ * N_);  // M*D
  ushort* y_bf    = hn_bf + (size_t)M_ * D_;            // M*E
  ushort* ub_bf   = y_bf + (size_t)M_ * E_;             // M*E
  ushort* xdbc_bf = ub_bf + (size_t)M_ * E_;            // M*64
  ushort* xwb     = xdbc_bf + (size_t)M_ * 64;          // NL*80*E
  ushort* dtwb    = xwb + (size_t)NL_ * XD_ * E_;       // NL*E*64
  ushort* in_wb   = dtwb + (size_t)NL_ * E_ * 64;       // E2*D (per-layer)
  ushort* out_wb  = in_wb + (size_t)E2_ * D_;           // D*E (per-layer)

  k_f2b<<<(NL_ * XD_ * E_ / 4 + 255) / 256, 256, 0, stream>>>(xproj_w, xwb, NL_ * XD_ * E_);
  k_dtpad<<<NL_ * E_ * 64 / 256, 256, 0, stream>>>(dt_w, dtwb);

  k_proj<<<dim3(D_ / 256, M_), 256, 0, stream>>>(x, proj_w, proj_b, h);

  for (int i = 0; i < NL_; i++) {
    k_f2b<<<(E2_ * D_ / 4 + 255) / 256, 256, 0, stream>>>(in_w + (size_t)i * E2_ * D_, in_wb, E2_ * D_);
    k_f2b<<<(D_ * E_ / 4 + 255) / 256, 256, 0, stream>>>(out_w + (size_t)i * D_ * E_, out_wb, D_ * E_);

    k_rmsnorm_bf<<<M_, 256, 0, stream>>>(h, norm_w + i * D_, hn_bf);
    k_gemm_bf<128, 128, 0><<<dim3(E2_ / 128, M_ / 128), 256, 0, stream>>>(hn_bf, in_wb, proj, nullptr, D_, E2_);
    k_conv<<<dim3(E_ / 256, M_), 256, 0, stream>>>(proj, conv_w + i * E_ * 4, conv_b + i * E_, ub, ub_bf);
    k_gemm_x<<<M_ / 64, 256, 0, stream>>>(ub_bf, xwb + (size_t)i * XD_ * E_, xdbc, xdbc_bf);
    k_gemm_bf<64, 128, 2><<<dim3(E_ / 128, M_ / 64), 256, 0, stream>>>(xdbc_bf, dtwb + (size_t)i * E_ * 64,
                                                                       dtbuf, dt_b + i * E_, 64, E_);
    k_scanA<<<dim3(E_ / 16, B_, NCH_), 256, 0, stream>>>(ub, dtbuf, xdbc,
                                                         A_log + (size_t)i * E_ * N_, Pst, Sst);
    k_scanB<<<B_ * E_ * N_ / 256, 256, 0, stream>>>(Pst, Sst, Hin);
    k_scanC<<<dim3(E_ / 16, B_, NCH_), 256, 0, stream>>>(ub, dtbuf, xdbc, proj,
                                                         A_log + (size_t)i * E_ * N_, D_param + i * E_,
                                                         Hin, y_bf);
    k_gemm_bf<64, 128, 1><<<dim3(D_ / 128, M_ / 64), 256, 0, stream>>>(y_bf, out_wb, h, h, E_, D_);
  }

  k_rowscale<<<M_, 256, 0, stream>>>(h, rsb);
  hipMemsetAsync(pooled, 0, (size_t)B_ * D_ * sizeof(float), stream);
  k_pool<<<dim3(D_ / 256, L_ / 128, B_), 256, 0, stream>>>(h, rsb, fnorm_w, pooled);
  k_logits<<<1, 256, 0, stream>>>(pooled, cls_w, cls_b, out);
}

// Round 5
// 735.990 us; speedup vs baseline: 4.6421x; 1.1191x over previous
//
#include <hip/hip_runtime.h>

// Problem constants (match reference)
constexpr int B_  = 2;
constexpr int L_  = 1024;
constexpr int D_  = 768;
constexpr int E_  = 1536;
constexpr int N_  = 16;
constexpr int R_  = 48;
constexpr int NL_ = 4;
constexpr int NC_ = 5;
constexpr int M_  = B_ * L_;        // 2048 token rows
constexpr int E2_ = 2 * E_;         // 3072
constexpr int XD_ = R_ + 2 * N_;    // 80
constexpr float EPS_ = 1e-5f;

constexpr int NCH_ = 16;            // time-chunks for parallel scan
constexpr int CL_  = L_ / NCH_;     // 64 timesteps per chunk
constexpr int TS_  = 32;            // LDS staging sub-chunk
constexpr int KS_  = 8;             // split-K factor for xproj GEMM

typedef __attribute__((ext_vector_type(8))) short bf16x8;
typedef __attribute__((ext_vector_type(4))) float f32x4;
typedef const __attribute__((address_space(1))) void* gas_t;
typedef __attribute__((address_space(3))) void* las_t;

__device__ __forceinline__ float sigm(float x) { return 1.0f / (1.0f + __expf(-x)); }
__device__ __forceinline__ float softplusf(float x) { return x > 20.0f ? x : log1pf(__expf(x)); }
__device__ __forceinline__ ushort f2b(float f) {  // fp32 -> bf16 RNE
  union { float f; unsigned u; } v; v.f = f;
  unsigned r = (v.u + 0x7fffu + ((v.u >> 16) & 1u)) >> 16;
  return (ushort)r;
}
__device__ __forceinline__ float b2f(ushort u) {
  union { unsigned u; float f; } v; v.u = ((unsigned)u) << 16;
  return v.f;
}

// DPP row_ror add: sum over 16-lane rows, full-rate VALU
template <int CTRL>
__device__ __forceinline__ float dpp_add(float x) {
  int yi = __builtin_amdgcn_update_dpp(0, __builtin_bit_cast(int, x), CTRL, 0xf, 0xf, false);
  return x + __builtin_bit_cast(float, yi);
}
__device__ __forceinline__ float row_sum16(float x) {
  x = dpp_add<0x121>(x);
  x = dpp_add<0x122>(x);
  x = dpp_add<0x124>(x);
  x = dpp_add<0x128>(x);
  return x;
}

__device__ __forceinline__ float block_sum(float v, float* sm) {
  #pragma unroll
  for (int o = 32; o > 0; o >>= 1) v += __shfl_xor(v, o);
  if ((threadIdx.x & 63) == 0) sm[threadIdx.x >> 6] = v;
  __syncthreads();
  return sm[0] + sm[1] + sm[2] + sm[3];
}

// fp32 -> bf16 bulk convert, n multiple of 4
__global__ __launch_bounds__(256) void k_f2b(const float* __restrict__ s, ushort* __restrict__ d, int nv) {
  int i = (blockIdx.x * 256 + threadIdx.x) * 4;
  if (i >= nv) return;
  float4 v = *(const float4*)(s + i);
  ushort4 o = make_ushort4(f2b(v.x), f2b(v.y), f2b(v.z), f2b(v.w));
  *(ushort4*)(d + i) = o;
}

// dt_w[NL][E][48] -> bf16 padded [NL][E][64]
__global__ __launch_bounds__(256) void k_dtpad(const float* __restrict__ dw, ushort* __restrict__ o) {
  int i = blockIdx.x * 256 + threadIdx.x;
  int k = i & 63, e = i >> 6;
  o[i] = (k < R_) ? f2b(dw[e * R_ + k]) : (ushort)0;
}

// h[m,d] = x[m,:12] @ proj_w[d,:12] + proj_b[d]
__global__ __launch_bounds__(256) void k_proj(const float* __restrict__ x, const float* __restrict__ pw,
                                              const float* __restrict__ pb, float* __restrict__ h) {
  __shared__ float xs[12];
  int m = blockIdx.y;
  int d = blockIdx.x * 256 + threadIdx.x;
  if (threadIdx.x < 12) xs[threadIdx.x] = x[m * 12 + threadIdx.x];
  __syncthreads();
  float acc = pb[d];
  #pragma unroll
  for (int j = 0; j < 12; j++) acc = fmaf(xs[j], pw[d * 12 + j], acc);
  h[(size_t)m * D_ + d] = acc;
}

// hn_bf16[m,:] = rmsnorm(h[m,:]) * w
__global__ __launch_bounds__(256) void k_rmsnorm_bf(const float* __restrict__ h, const float* __restrict__ w,
                                                    ushort* __restrict__ hn) {
  __shared__ float sm[4];
  int m = blockIdx.x, tid = threadIdx.x;
  const float* row = h + (size_t)m * D_;
  float v0 = row[tid], v1 = row[tid + 256], v2 = row[tid + 512];
  float s = block_sum(v0 * v0 + v1 * v1 + v2 * v2, sm);
  float sc = rsqrtf(s * (1.0f / D_) + EPS_);
  ushort* o = hn + (size_t)m * D_;
  o[tid]       = f2b(v0 * sc * w[tid]);
  o[tid + 256] = f2b(v1 * sc * w[tid + 256]);
  o[tid + 512] = f2b(v2 * sc * w[tid + 512]);
}

// C[M,Nd] = A_bf16[M,Kd] @ Bw_bf16[Nd,Kd]^T. MFMA 16x16x32 bf16.
// MODE 0: C=v   MODE 1: C=v+res[off]   MODE 2: C=softplus(v+res[col]) (res=bias)
template <int BM, int BN, int MODE>
__global__ __launch_bounds__(256) void k_gemm_bf(const ushort* __restrict__ A, const ushort* __restrict__ Bw,
                                                 float* __restrict__ C, const float* __restrict__ res,
                                                 int Kd, int Nd) {
  constexpr int AM = BM / 32, BNF = BN / 32;
  __shared__ ushort sA[BM * 32];
  __shared__ ushort sB[BN * 32];
  const int tid = threadIdx.x;
  const int wave = tid >> 6, lane = tid & 63;
  const int q = lane >> 4, r = lane & 15;
  const int wm = wave >> 1, wn = wave & 1;
  const int m0 = blockIdx.y * BM, n0 = blockIdx.x * BN;
  f32x4 acc[AM][BNF] = {};

  for (int k0 = 0; k0 < Kd; k0 += 32) {
    #pragma unroll
    for (int j = 0; j < BM / 64; j++) {
      int i = j * 256 + tid;
      const ushort* gp = A + (size_t)(m0 + (i >> 2)) * Kd + k0 + ((i & 3) << 3);
      __builtin_amdgcn_global_load_lds((gas_t)gp, (las_t)(sA + ((j * 256 + wave * 64) << 3)), 16, 0, 0);
    }
    #pragma unroll
    for (int j = 0; j < BN / 64; j++) {
      int i = j * 256 + tid;
      const ushort* gp = Bw + (size_t)(n0 + (i >> 2)) * Kd + k0 + ((i & 3) << 3);
      __builtin_amdgcn_global_load_lds((gas_t)gp, (las_t)(sB + ((j * 256 + wave * 64) << 3)), 16, 0, 0);
    }
    __syncthreads();
    bf16x8 af[AM], bfv[BNF];
    #pragma unroll
    for (int mi = 0; mi < AM; mi++)
      af[mi] = *(const bf16x8*)&sA[(wm * (BM / 2) + mi * 16 + r) * 32 + q * 8];
    #pragma unroll
    for (int nj = 0; nj < BNF; nj++)
      bfv[nj] = *(const bf16x8*)&sB[(wn * (BN / 2) + nj * 16 + r) * 32 + q * 8];
    #pragma unroll
    for (int mi = 0; mi < AM; mi++)
      #pragma unroll
      for (int nj = 0; nj < BNF; nj++)
        acc[mi][nj] = __builtin_amdgcn_mfma_f32_16x16x32_bf16(af[mi], bfv[nj], acc[mi][nj], 0, 0, 0);
    __syncthreads();
  }
  #pragma unroll
  for (int mi = 0; mi < AM; mi++) {
    #pragma unroll
    for (int nj = 0; nj < BNF; nj++) {
      int col = n0 + wn * (BN / 2) + nj * 16 + r;
      #pragma unroll
      for (int rg = 0; rg < 4; rg++) {
        int row = m0 + wm * (BM / 2) + mi * 16 + q * 4 + rg;
        size_t off = (size_t)row * Nd + col;
        float v = acc[mi][nj][rg];
        if (MODE == 1) v += res[off];
        if (MODE == 2) v = softplusf(v + res[col]);
        C[off] = v;
      }
    }
  }
}

// xproj GEMM, split-K: part[ks][M][80] = u_bf[M, ks-slice] @ xwb[80, ks-slice]^T
__global__ __launch_bounds__(256) void k_gemm_x(const ushort* __restrict__ A, const ushort* __restrict__ Bw,
                                                float* __restrict__ part) {
  __shared__ ushort sA[64 * 32];
  __shared__ ushort sB[80 * 32];
  const int tid = threadIdx.x;
  const int wave = tid >> 6, lane = tid & 63;
  const int q = lane >> 4, r = lane & 15;
  const int m0 = blockIdx.x * 64;
  const int kbeg = blockIdx.y * (E_ / KS_), kend = kbeg + E_ / KS_;
  f32x4 acc[5] = {};

  for (int k0 = kbeg; k0 < kend; k0 += 32) {
    {
      const ushort* gp = A + (size_t)(m0 + wave * 16 + (lane >> 2)) * E_ + k0 + ((lane & 3) << 3);
      __builtin_amdgcn_global_load_lds((gas_t)gp, (las_t)(sA + (wave << 9)), 16, 0, 0);
    }
    #pragma unroll
    for (int j = wave; j < 5; j += 4) {
      const ushort* gp = Bw + (size_t)(j * 16 + (lane >> 2)) * E_ + k0 + ((lane & 3) << 3);
      __builtin_amdgcn_global_load_lds((gas_t)gp, (las_t)(sB + (j << 9)), 16, 0, 0);
    }
    __syncthreads();
    bf16x8 af = *(const bf16x8*)&sA[(wave * 16 + r) * 32 + q * 8];
    #pragma unroll
    for (int nj = 0; nj < 5; nj++) {
      bf16x8 bfv = *(const bf16x8*)&sB[(nj * 16 + r) * 32 + q * 8];
      acc[nj] = __builtin_amdgcn_mfma_f32_16x16x32_bf16(af, bfv, acc[nj], 0, 0, 0);
    }
    __syncthreads();
  }
  float* pp = part + (size_t)blockIdx.y * M_ * XD_;
  #pragma unroll
  for (int nj = 0; nj < 5; nj++) {
    int col = nj * 16 + r;
    #pragma unroll
    for (int rg = 0; rg < 4; rg++) {
      int row = m0 + wave * 16 + q * 4 + rg;
      pp[(size_t)row * XD_ + col] = acc[nj][rg];
    }
  }
}

// combine split-K partials -> xdbc fp32 [M][80] + bf16 dt-input copy [M][64]
__global__ __launch_bounds__(256) void k_xfin(const float* __restrict__ part, float* __restrict__ xdbc,
                                              ushort* __restrict__ xb) {
  int i = blockIdx.x * 256 + threadIdx.x;   // over M*80
  int m = i / XD_, col = i - m * XD_;
  float s = 0.0f;
  #pragma unroll
  for (int ks = 0; ks < KS_; ks++) s += part[(size_t)ks * M_ * XD_ + i];
  xdbc[i] = s;
  if (col < R_) xb[(size_t)m * 64 + col] = f2b(s);
  else if (col < 64) xb[(size_t)m * 64 + col] = 0;
}

// u[m,e] = silu(conv...), bf16 output only
__global__ __launch_bounds__(256) void k_conv(const float* __restrict__ proj, const float* __restrict__ cw,
                                              const float* __restrict__ cb, ushort* __restrict__ ub16) {
  int m = blockIdx.y;
  int b = m >> 10, t = m & (L_ - 1);
  int e = blockIdx.x * 256 + threadIdx.x;
  float4 w = *(const float4*)(cw + e * 4);
  float wr[4] = {w.x, w.y, w.z, w.w};
  float acc = cb[e];
  #pragma unroll
  for (int k = 0; k < 4; k++) {
    int tt = t + k - 3;
    if (tt >= 0) acc = fmaf(wr[k], proj[(size_t)(b * L_ + tt) * E2_ + e], acc);
  }
  float uv = acc * sigm(acc);
  ub16[(size_t)m * E_ + e] = f2b(uv);
}

// ---- Parallel (chunked) selective scan --------------------------------------
// Phase A: per (e-tile, b, chunk): local scan from h=0 -> P=prod(dA), S=h_end.
// Phase C: inline lookback combine of predecessor summaries, re-scan, emit y.

__global__ __launch_bounds__(256) void k_scanA(const ushort* __restrict__ u, const float* __restrict__ dtb,
                                               const float* __restrict__ xdbc, const float* __restrict__ A_log,
                                               float* __restrict__ Pst, float* __restrict__ Sst) {
  __shared__ float2 s_dtu[2][TS_][16];   // (dt, dt*u)
  __shared__ float  s_b [2][TS_][16];    // B_n
  const int tid = threadIdx.x;
  const int e0 = blockIdx.x << 4;
  const int b  = blockIdx.y;
  const int c  = blockIdx.z;
  const int n  = tid & 15, el = tid >> 4;
  const int e  = e0 + el;
  const float A = -__expf(A_log[e * N_ + n]);
  const int se = tid & 15, st = tid >> 4;

  float r_dt[2], r_b[2];
  ushort r_u[2];
  auto issue = [&](int s) {
    int t0 = c * CL_ + s * TS_;
    #pragma unroll
    for (int j = 0; j < 2; j++) {
      size_t m = (size_t)(b * L_ + t0 + j * 16 + st);
      r_dt[j] = dtb[m * E_ + e0 + se];
      r_u[j]  = u[m * E_ + e0 + se];
    }
    #pragma unroll
    for (int j = 0; j < 2; j++) {
      int idx = j * 256 + tid;
      r_b[j] = xdbc[(size_t)(b * L_ + t0 + (idx >> 4)) * XD_ + R_ + (idx & 15)];
    }
  };
  auto commit = [&](int pb) {
    #pragma unroll
    for (int j = 0; j < 2; j++) {
      int t = j * 16 + st;
      s_dtu[pb][t][se] = make_float2(r_dt[j], r_dt[j] * b2f(r_u[j]));
    }
    #pragma unroll
    for (int j = 0; j < 2; j++) {
      int idx = j * 256 + tid;
      s_b[pb][idx >> 4][idx & 15] = r_b[j];
    }
  };

  issue(0);
  commit(0);
  float hs = 0.0f, pp = 1.0f;
  constexpr int NS = CL_ / TS_;
  for (int s = 0; s < NS; s++) {
    __syncthreads();
    if (s + 1 < NS) issue(s + 1);
    const int pb = s & 1;
    #pragma unroll
    for (int t = 0; t < TS_; t++) {
      float2 dtu = s_dtu[pb][t][el];
      float bv   = s_b[pb][t][n];
      float dA = __expf(dtu.x * A);
      hs = fmaf(hs, dA, dtu.y * bv);
      pp *= dA;
    }
    if (s + 1 < NS) commit((s + 1) & 1);
  }
  size_t o = (((size_t)(b * NCH_ + c) * E_) + e) * N_ + n;
  Pst[o] = pp;
  Sst[o] = hs;
}

__global__ __launch_bounds__(256) void k_scanC(const ushort* __restrict__ u, const float* __restrict__ dtb,
                                               const float* __restrict__ xdbc, const float* __restrict__ proj,
                                               const float* __restrict__ A_log, const float* __restrict__ Dp,
                                               const float* __restrict__ Pst, const float* __restrict__ Sst,
                                               ushort* __restrict__ y) {
  __shared__ float2 s_dtu[2][TS_][16];   // (dt, dt*u)
  __shared__ float2 s_bc [2][TS_][16];   // (B_n, C_n)
  __shared__ float2 s_og [2][TS_][16];   // (u*D, silu(gate))
  const int tid = threadIdx.x;
  const int e0 = blockIdx.x << 4;
  const int b  = blockIdx.y;
  const int c  = blockIdx.z;
  const int n  = tid & 15, el = tid >> 4;
  const int e  = e0 + el;
  const float A = -__expf(A_log[e * N_ + n]);
  const int se = tid & 15, st = tid >> 4;
  const float Dv = Dp[e0 + se];

  float r_dt[2], r_g[2], r_bc[4];
  ushort r_u[2];
  auto issue = [&](int s) {
    int t0 = c * CL_ + s * TS_;
    #pragma unroll
    for (int j = 0; j < 2; j++) {
      size_t m = (size_t)(b * L_ + t0 + j * 16 + st);
      r_dt[j] = dtb[m * E_ + e0 + se];
      r_u[j]  = u[m * E_ + e0 + se];
      r_g[j]  = proj[m * E2_ + E_ + e0 + se];
    }
    #pragma unroll
    for (int j = 0; j < 4; j++) {
      int idx = j * 256 + tid;
      r_bc[j] = xdbc[(size_t)(b * L_ + t0 + (idx >> 5)) * XD_ + R_ + (idx & 31)];
    }
  };
  auto commit = [&](int pb) {
    #pragma unroll
    for (int j = 0; j < 2; j++) {
      int t = j * 16 + st;
      float uf = b2f(r_u[j]);
      s_dtu[pb][t][se] = make_float2(r_dt[j], r_dt[j] * uf);
      float g = r_g[j];
      s_og[pb][t][se] = make_float2(uf * Dv, g * sigm(g));
    }
    #pragma unroll
    for (int j = 0; j < 4; j++) {
      int idx = j * 256 + tid;
      int t = idx >> 5, col = idx & 31;
      ((float*)&s_bc[pb][t][0])[((col & 15) << 1) + (col >> 4)] = r_bc[j];
    }
  };

  issue(0);
  // inline lookback: h_in = sequential combine of predecessor chunk summaries
  float hs = 0.0f;
  for (int cc = 0; cc < c; cc++) {
    size_t o = (((size_t)(b * NCH_ + cc) * E_) + e) * N_ + n;
    hs = fmaf(Pst[o], hs, Sst[o]);
  }
  commit(0);
  constexpr int NS = CL_ / TS_;
  for (int s = 0; s < NS; s++) {
    __syncthreads();
    if (s + 1 < NS) issue(s + 1);
    const int pb = s & 1;
    const int mbase = b * L_ + c * CL_ + s * TS_;
    #pragma unroll
    for (int t = 0; t < TS_; t++) {
      float2 dtu = s_dtu[pb][t][el];
      float2 bc  = s_bc[pb][t][n];
      float dA = __expf(dtu.x * A);
      hs = fmaf(hs, dA, dtu.y * bc.x);
      float p = row_sum16(hs * bc.y);
      if (n == 0) {
        float2 og = s_og[pb][t][el];
        y[(size_t)(mbase + t) * E_ + e] = f2b((p + og.x) * og.y);
      }
    }
    if (s + 1 < NS) commit((s + 1) & 1);
  }
}

// rs[m] = rsqrt(mean(h[m,:]^2)+eps)
__global__ __launch_bounds__(256) void k_rowscale(const float* __restrict__ h, float* __restrict__ rs) {
  __shared__ float sm[4];
  int m = blockIdx.x, tid = threadIdx.x;
  const float* row = h + (size_t)m * D_;
  float v0 = row[tid], v1 = row[tid + 256], v2 = row[tid + 512];
  float s = block_sum(v0 * v0 + v1 * v1 + v2 * v2, sm);
  if (tid == 0) rs[m] = rsqrtf(s * (1.0f / D_) + EPS_);
}

// pooled[b,d] += fnorm_w[d]/L * sum_t h[b,t,d]*rs[b,t]
__global__ __launch_bounds__(256) void k_pool(const float* __restrict__ h, const float* __restrict__ rs,
                                              const float* __restrict__ fw, float* __restrict__ pooled) {
  int d = blockIdx.x * 256 + threadIdx.x;
  int t0 = blockIdx.y * 128;
  int b = blockIdx.z;
  float acc = 0.0f;
  for (int t = t0; t < t0 + 128; t++) {
    int m = b * L_ + t;
    acc = fmaf(h[(size_t)m * D_ + d], rs[m], acc);
  }
  atomicAdd(&pooled[b * D_ + d], acc * fw[d] * (1.0f / L_));
}

// out[b,c] = pooled[b,:] @ cls_w[c,:] + cls_b[c]
__global__ __launch_bounds__(256) void k_logits(const float* __restrict__ pooled, const float* __restrict__ cw,
                                                const float* __restrict__ cb, float* __restrict__ out) {
  int wv = threadIdx.x >> 6, ln = threadIdx.x & 63;
  for (int p = wv; p < B_ * NC_; p += 4) {
    int b = p / NC_, c = p % NC_;
    float s = 0.0f;
    for (int d = ln; d < D_; d += 64) s = fmaf(pooled[b * D_ + d], cw[c * D_ + d], s);
    #pragma unroll
    for (int o = 32; o > 0; o >>= 1) s += __shfl_xor(s, o);
    if (ln == 0) out[p] = s + cb[c];
  }
}

extern "C" void kernel_launch(void* const* d_in, const int* in_sizes, int n_in,
                              void* d_out, int out_size, void* d_ws, size_t ws_size,
                              hipStream_t stream) {
  const float* x       = (const float*)d_in[0];
  const float* proj_w  = (const float*)d_in[1];
  const float* proj_b  = (const float*)d_in[2];
  const float* norm_w  = (const float*)d_in[3];
  const float* in_w    = (const float*)d_in[4];
  const float* conv_w  = (const float*)d_in[5];
  const float* conv_b  = (const float*)d_in[6];
  const float* xproj_w = (const float*)d_in[7];
  const float* dt_w    = (const float*)d_in[8];
  const float* dt_b    = (const float*)d_in[9];
  const float* A_log   = (const float*)d_in[10];
  const float* D_param = (const float*)d_in[11];
  const float* out_w   = (const float*)d_in[12];
  const float* fnorm_w = (const float*)d_in[13];
  const float* cls_w   = (const float*)d_in[14];
  const float* cls_b   = (const float*)d_in[15];
  float* out = (float*)d_out;

  // workspace layout
  float* h      = (float*)d_ws;                         // M*D
  float* proj   = h + (size_t)M_ * D_;                  // M*2E
  float* xdbc   = proj + (size_t)M_ * E2_;              // M*80
  float* dtbuf  = xdbc + (size_t)M_ * XD_;              // M*E
  float* rsb    = dtbuf + (size_t)M_ * E_;              // M
  float* pooled = rsb + M_;                             // B*D
  float* Pst    = pooled + B_ * D_;                     // B*NCH*E*N
  float* Sst    = Pst + (size_t)B_ * NCH_ * E_ * N_;    // B*NCH*E*N
  float* xpart  = Sst + (size_t)B_ * NCH_ * E_ * N_;    // KS*M*80
  ushort* hn_bf   = (ushort*)(xpart + (size_t)KS_ * M_ * XD_);  // M*D
  ushort* y_bf    = hn_bf + (size_t)M_ * D_;            // M*E
  ushort* ub_bf   = y_bf + (size_t)M_ * E_;             // M*E
  ushort* xdbc_bf = ub_bf + (size_t)M_ * E_;            // M*64
  ushort* xwb     = xdbc_bf + (size_t)M_ * 64;          // NL*80*E
  ushort* dtwb    = xwb + (size_t)NL_ * XD_ * E_;       // NL*E*64
  ushort* in_wb   = dtwb + (size_t)NL_ * E_ * 64;       // NL*E2*D
  ushort* out_wb  = in_wb + (size_t)NL_ * E2_ * D_;     // NL*D*E

  // one-time weight conversions (all layers)
  k_f2b<<<(NL_ * XD_ * E_ / 4 + 255) / 256, 256, 0, stream>>>(xproj_w, xwb, NL_ * XD_ * E_);
  k_dtpad<<<NL_ * E_ * 64 / 256, 256, 0, stream>>>(dt_w, dtwb);
  k_f2b<<<(NL_ * E2_ * D_ / 4 + 255) / 256, 256, 0, stream>>>(in_w, in_wb, NL_ * E2_ * D_);
  k_f2b<<<(NL_ * D_ * E_ / 4 + 255) / 256, 256, 0, stream>>>(out_w, out_wb, NL_ * D_ * E_);

  k_proj<<<dim3(D_ / 256, M_), 256, 0, stream>>>(x, proj_w, proj_b, h);

  for (int i = 0; i < NL_; i++) {
    k_rmsnorm_bf<<<M_, 256, 0, stream>>>(h, norm_w + i * D_, hn_bf);
    k_gemm_bf<128, 128, 0><<<dim3(E2_ / 128, M_ / 128), 256, 0, stream>>>(
        hn_bf, in_wb + (size_t)i * E2_ * D_, proj, nullptr, D_, E2_);
    k_conv<<<dim3(E_ / 256, M_), 256, 0, stream>>>(proj, conv_w + i * E_ * 4, conv_b + i * E_, ub_bf);
    k_gemm_x<<<dim3(M_ / 64, KS_), 256, 0, stream>>>(ub_bf, xwb + (size_t)i * XD_ * E_, xpart);
    k_xfin<<<M_ * XD_ / 256, 256, 0, stream>>>(xpart, xdbc, xdbc_bf);
    k_gemm_bf<64, 128, 2><<<dim3(E_ / 128, M_ / 64), 256, 0, stream>>>(
        xdbc_bf, dtwb + (size_t)i * E_ * 64, dtbuf, dt_b + i * E_, 64, E_);
    k_scanA<<<dim3(E_ / 16, B_, NCH_), 256, 0, stream>>>(ub_bf, dtbuf, xdbc,
                                                         A_log + (size_t)i * E_ * N_, Pst, Sst);
    k_scanC<<<dim3(E_ / 16, B_, NCH_), 256, 0, stream>>>(ub_bf, dtbuf, xdbc, proj,
                                                         A_log + (size_t)i * E_ * N_, D_param + i * E_,
                                                         Pst, Sst, y_bf);
    k_gemm_bf<64, 128, 1><<<dim3(D_ / 128, M_ / 64), 256, 0, stream>>>(
        y_bf, out_wb + (size_t)i * D_ * E_, h, h, E_, D_);
  }

  k_rowscale<<<M_, 256, 0, stream>>>(h, rsb);
  hipMemsetAsync(pooled, 0, (size_t)B_ * D_ * sizeof(float), stream);
  k_pool<<<dim3(D_ / 256, L_ / 128, B_), 256, 0, stream>>>(h, rsb, fnorm_w, pooled);
  k_logits<<<1, 256, 0, stream>>>(pooled, cls_w, cls_b, out);
}

// Round 6
// 692.228 us; speedup vs baseline: 4.9356x; 1.0632x over previous
//
#include <hip/hip_runtime.h>

// Problem constants (match reference)
constexpr int B_  = 2;
constexpr int L_  = 1024;
constexpr int D_  = 768;
constexpr int E_  = 1536;
constexpr int N_  = 16;
constexpr int R_  = 48;
constexpr int NL_ = 4;
constexpr int NC_ = 5;
constexpr int M_  = B_ * L_;        // 2048 token rows
constexpr int E2_ = 2 * E_;         // 3072
constexpr int XD_ = R_ + 2 * N_;    // 80
constexpr float EPS_ = 1e-5f;

constexpr int NCH_ = 16;            // time-chunks for parallel scan
constexpr int CL_  = L_ / NCH_;     // 64 timesteps per chunk
constexpr int TS_  = 32;            // LDS staging sub-chunk
constexpr int KS_  = 8;             // split-K factor for xproj GEMM

typedef __attribute__((ext_vector_type(8))) short bf16x8;
typedef __attribute__((ext_vector_type(4))) float f32x4;
typedef const __attribute__((address_space(1))) void* gas_t;
typedef __attribute__((address_space(3))) void* las_t;

__device__ __forceinline__ float sigm(float x) { return 1.0f / (1.0f + __expf(-x)); }
__device__ __forceinline__ float softplusf(float x) { return x > 20.0f ? x : log1pf(__expf(x)); }
__device__ __forceinline__ ushort f2b(float f) {  // fp32 -> bf16 RNE
  union { float f; unsigned u; } v; v.f = f;
  unsigned r = (v.u + 0x7fffu + ((v.u >> 16) & 1u)) >> 16;
  return (ushort)r;
}
__device__ __forceinline__ float b2f(ushort u) {
  union { unsigned u; float f; } v; v.u = ((unsigned)u) << 16;
  return v.f;
}
__device__ __forceinline__ float b2f_lo(unsigned p) {
  union { unsigned u; float f; } v; v.u = p << 16;
  return v.f;
}
__device__ __forceinline__ float b2f_hi(unsigned p) {
  union { unsigned u; float f; } v; v.u = p & 0xffff0000u;
  return v.f;
}

// DPP row_ror add: sum over 16-lane rows, full-rate VALU
template <int CTRL>
__device__ __forceinline__ float dpp_add(float x) {
  int yi = __builtin_amdgcn_update_dpp(0, __builtin_bit_cast(int, x), CTRL, 0xf, 0xf, false);
  return x + __builtin_bit_cast(float, yi);
}
__device__ __forceinline__ float row_sum16(float x) {
  x = dpp_add<0x121>(x);
  x = dpp_add<0x122>(x);
  x = dpp_add<0x124>(x);
  x = dpp_add<0x128>(x);
  return x;
}

__device__ __forceinline__ float block_sum(float v, float* sm) {
  #pragma unroll
  for (int o = 32; o > 0; o >>= 1) v += __shfl_xor(v, o);
  if ((threadIdx.x & 63) == 0) sm[threadIdx.x >> 6] = v;
  __syncthreads();
  return sm[0] + sm[1] + sm[2] + sm[3];
}

// One-shot weight prep: in_w, out_w, xproj_w plain f2b; dt_w padded 48->64
constexpr int WS1_ = NL_ * E2_ * D_;        // in_w
constexpr int WS2_ = NL_ * D_ * E_;         // out_w
constexpr int WS3_ = NL_ * XD_ * E_;        // xproj_w
constexpr int WS4_ = NL_ * E_ * 64;         // dt_w padded
__global__ __launch_bounds__(256) void k_wprep(const float* __restrict__ in_w, const float* __restrict__ out_w,
                                               const float* __restrict__ xw, const float* __restrict__ dw,
                                               ushort* __restrict__ in_wb, ushort* __restrict__ out_wb,
                                               ushort* __restrict__ xwb, ushort* __restrict__ dtwb) {
  int i = (blockIdx.x * 256 + threadIdx.x) * 4;
  if (i < WS1_) {
    float4 v = *(const float4*)(in_w + i);
    *(ushort4*)(in_wb + i) = make_ushort4(f2b(v.x), f2b(v.y), f2b(v.z), f2b(v.w));
  } else if (i < WS1_ + WS2_) {
    int j = i - WS1_;
    float4 v = *(const float4*)(out_w + j);
    *(ushort4*)(out_wb + j) = make_ushort4(f2b(v.x), f2b(v.y), f2b(v.z), f2b(v.w));
  } else if (i < WS1_ + WS2_ + WS3_) {
    int j = i - WS1_ - WS2_;
    float4 v = *(const float4*)(xw + j);
    *(ushort4*)(xwb + j) = make_ushort4(f2b(v.x), f2b(v.y), f2b(v.z), f2b(v.w));
  } else if (i < WS1_ + WS2_ + WS3_ + WS4_) {
    int j = i - WS1_ - WS2_ - WS3_;
    int k = j & 63, e = j >> 6;
    ushort4 o;
    o.x = (k + 0 < R_) ? f2b(dw[e * R_ + k + 0]) : (ushort)0;
    o.y = (k + 1 < R_) ? f2b(dw[e * R_ + k + 1]) : (ushort)0;
    o.z = (k + 2 < R_) ? f2b(dw[e * R_ + k + 2]) : (ushort)0;
    o.w = (k + 3 < R_) ? f2b(dw[e * R_ + k + 3]) : (ushort)0;
    *(ushort4*)(dtwb + j) = o;
  }
}

// h[m,d] = x[m,:12] @ proj_w[d,:12] + proj_b[d]
__global__ __launch_bounds__(256) void k_proj(const float* __restrict__ x, const float* __restrict__ pw,
                                              const float* __restrict__ pb, float* __restrict__ h) {
  __shared__ float xs[12];
  int m = blockIdx.y;
  int d = blockIdx.x * 256 + threadIdx.x;
  if (threadIdx.x < 12) xs[threadIdx.x] = x[m * 12 + threadIdx.x];
  __syncthreads();
  float acc = pb[d];
  #pragma unroll
  for (int j = 0; j < 12; j++) acc = fmaf(xs[j], pw[d * 12 + j], acc);
  h[(size_t)m * D_ + d] = acc;
}

// hn_bf16[m,:] = rmsnorm(h[m,:]) * w
__global__ __launch_bounds__(256) void k_rmsnorm_bf(const float* __restrict__ h, const float* __restrict__ w,
                                                    ushort* __restrict__ hn) {
  __shared__ float sm[4];
  int m = blockIdx.x, tid = threadIdx.x;
  const float* row = h + (size_t)m * D_;
  float v0 = row[tid], v1 = row[tid + 256], v2 = row[tid + 512];
  float s = block_sum(v0 * v0 + v1 * v1 + v2 * v2, sm);
  float sc = rsqrtf(s * (1.0f / D_) + EPS_);
  ushort* o = hn + (size_t)m * D_;
  o[tid]       = f2b(v0 * sc * w[tid]);
  o[tid + 256] = f2b(v1 * sc * w[tid + 256]);
  o[tid + 512] = f2b(v2 * sc * w[tid + 512]);
}

// C[M,Nd] = A_bf16[M,Kd] @ Bw_bf16[Nd,Kd]^T. MFMA 16x16x32 bf16.
// MODE 0: fp32 C=v  MODE 1: fp32 C=v+res[off]  MODE 2: fp32 C=softplus(v+res[col])
// MODE 3: bf16 C=v
template <int BM, int BN, int MODE>
__global__ __launch_bounds__(256) void k_gemm_bf(const ushort* __restrict__ A, const ushort* __restrict__ Bw,
                                                 void* __restrict__ Cv, const float* __restrict__ res,
                                                 int Kd, int Nd) {
  constexpr int AM = BM / 32, BNF = BN / 32;
  __shared__ ushort sA[BM * 32];
  __shared__ ushort sB[BN * 32];
  const int tid = threadIdx.x;
  const int wave = tid >> 6, lane = tid & 63;
  const int q = lane >> 4, r = lane & 15;
  const int wm = wave >> 1, wn = wave & 1;
  const int m0 = blockIdx.y * BM, n0 = blockIdx.x * BN;
  f32x4 acc[AM][BNF] = {};

  for (int k0 = 0; k0 < Kd; k0 += 32) {
    #pragma unroll
    for (int j = 0; j < BM / 64; j++) {
      int i = j * 256 + tid;
      const ushort* gp = A + (size_t)(m0 + (i >> 2)) * Kd + k0 + ((i & 3) << 3);
      __builtin_amdgcn_global_load_lds((gas_t)gp, (las_t)(sA + ((j * 256 + wave * 64) << 3)), 16, 0, 0);
    }
    #pragma unroll
    for (int j = 0; j < BN / 64; j++) {
      int i = j * 256 + tid;
      const ushort* gp = Bw + (size_t)(n0 + (i >> 2)) * Kd + k0 + ((i & 3) << 3);
      __builtin_amdgcn_global_load_lds((gas_t)gp, (las_t)(sB + ((j * 256 + wave * 64) << 3)), 16, 0, 0);
    }
    __syncthreads();
    bf16x8 af[AM], bfv[BNF];
    #pragma unroll
    for (int mi = 0; mi < AM; mi++)
      af[mi] = *(const bf16x8*)&sA[(wm * (BM / 2) + mi * 16 + r) * 32 + q * 8];
    #pragma unroll
    for (int nj = 0; nj < BNF; nj++)
      bfv[nj] = *(const bf16x8*)&sB[(wn * (BN / 2) + nj * 16 + r) * 32 + q * 8];
    #pragma unroll
    for (int mi = 0; mi < AM; mi++)
      #pragma unroll
      for (int nj = 0; nj < BNF; nj++)
        acc[mi][nj] = __builtin_amdgcn_mfma_f32_16x16x32_bf16(af[mi], bfv[nj], acc[mi][nj], 0, 0, 0);
    __syncthreads();
  }
  // C/D layout: col = lane&15, row = (lane>>4)*4 + reg
  #pragma unroll
  for (int mi = 0; mi < AM; mi++) {
    #pragma unroll
    for (int nj = 0; nj < BNF; nj++) {
      int col = n0 + wn * (BN / 2) + nj * 16 + r;
      #pragma unroll
      for (int rg = 0; rg < 4; rg++) {
        int row = m0 + wm * (BM / 2) + mi * 16 + q * 4 + rg;
        size_t off = (size_t)row * Nd + col;
        float v = acc[mi][nj][rg];
        if (MODE == 3) {
          ((ushort*)Cv)[off] = f2b(v);
        } else {
          if (MODE == 1) v += res[off];
          if (MODE == 2) v = softplusf(v + res[col]);
          ((float*)Cv)[off] = v;
        }
      }
    }
  }
}

// xproj GEMM, split-K: part[ks][M][80] = u_bf[M, ks-slice] @ xwb[80, ks-slice]^T
__global__ __launch_bounds__(256) void k_gemm_x(const ushort* __restrict__ A, const ushort* __restrict__ Bw,
                                                float* __restrict__ part) {
  __shared__ ushort sA[64 * 32];
  __shared__ ushort sB[80 * 32];
  const int tid = threadIdx.x;
  const int wave = tid >> 6, lane = tid & 63;
  const int q = lane >> 4, r = lane & 15;
  const int m0 = blockIdx.x * 64;
  const int kbeg = blockIdx.y * (E_ / KS_), kend = kbeg + E_ / KS_;
  f32x4 acc[5] = {};

  for (int k0 = kbeg; k0 < kend; k0 += 32) {
    {
      const ushort* gp = A + (size_t)(m0 + wave * 16 + (lane >> 2)) * E_ + k0 + ((lane & 3) << 3);
      __builtin_amdgcn_global_load_lds((gas_t)gp, (las_t)(sA + (wave << 9)), 16, 0, 0);
    }
    #pragma unroll
    for (int j = wave; j < 5; j += 4) {
      const ushort* gp = Bw + (size_t)(j * 16 + (lane >> 2)) * E_ + k0 + ((lane & 3) << 3);
      __builtin_amdgcn_global_load_lds((gas_t)gp, (las_t)(sB + (j << 9)), 16, 0, 0);
    }
    __syncthreads();
    bf16x8 af = *(const bf16x8*)&sA[(wave * 16 + r) * 32 + q * 8];
    #pragma unroll
    for (int nj = 0; nj < 5; nj++) {
      bf16x8 bfv = *(const bf16x8*)&sB[(nj * 16 + r) * 32 + q * 8];
      acc[nj] = __builtin_amdgcn_mfma_f32_16x16x32_bf16(af, bfv, acc[nj], 0, 0, 0);
    }
    __syncthreads();
  }
  float* pp = part + (size_t)blockIdx.y * M_ * XD_;
  #pragma unroll
  for (int nj = 0; nj < 5; nj++) {
    int col = nj * 16 + r;
    #pragma unroll
    for (int rg = 0; rg < 4; rg++) {
      int row = m0 + wave * 16 + q * 4 + rg;
      pp[(size_t)row * XD_ + col] = acc[nj][rg];
    }
  }
}

// combine split-K partials -> xdbc fp32 [M][80] + bf16 dt-input copy [M][64]
__global__ __launch_bounds__(256) void k_xfin(const float* __restrict__ part, float* __restrict__ xdbc,
                                              ushort* __restrict__ xb) {
  int i = blockIdx.x * 256 + threadIdx.x;   // over M*80
  int m = i / XD_, col = i - m * XD_;
  float s = 0.0f;
  #pragma unroll
  for (int ks = 0; ks < KS_; ks++) s += part[(size_t)ks * M_ * XD_ + i];
  xdbc[i] = s;
  if (col < R_) xb[(size_t)m * 64 + col] = f2b(s);
  else if (col < 64) xb[(size_t)m * 64 + col] = 0;
}

// conv + silu for u; silu for gate. bf16 in (proj_bf), bf16 out. 4 e / thread.
__global__ __launch_bounds__(384) void k_conv2(const ushort* __restrict__ proj, const float* __restrict__ cw,
                                               const float* __restrict__ cb, ushort* __restrict__ ub16,
                                               ushort* __restrict__ gb16) {
  int m = blockIdx.x;
  int b = m >> 10, t = m & (L_ - 1);
  int e4 = threadIdx.x * 4;
  float wv[4][4];
  #pragma unroll
  for (int j = 0; j < 4; j++) {
    float4 w = *(const float4*)(cw + (e4 + j) * 4);
    wv[j][0] = w.x; wv[j][1] = w.y; wv[j][2] = w.z; wv[j][3] = w.w;
  }
  float4 bb = *(const float4*)(cb + e4);
  float acc[4] = {bb.x, bb.y, bb.z, bb.w};
  #pragma unroll
  for (int k = 0; k < 4; k++) {
    int tt = t + k - 3;
    if (tt >= 0) {
      uint2 p = *(const uint2*)(proj + (size_t)(b * L_ + tt) * E2_ + e4);
      acc[0] = fmaf(wv[0][k], b2f_lo(p.x), acc[0]);
      acc[1] = fmaf(wv[1][k], b2f_hi(p.x), acc[1]);
      acc[2] = fmaf(wv[2][k], b2f_lo(p.y), acc[2]);
      acc[3] = fmaf(wv[3][k], b2f_hi(p.y), acc[3]);
    }
  }
  uint2 uo;
  {
    float u0 = acc[0] * sigm(acc[0]), u1 = acc[1] * sigm(acc[1]);
    float u2 = acc[2] * sigm(acc[2]), u3 = acc[3] * sigm(acc[3]);
    uo.x = (unsigned)f2b(u0) | ((unsigned)f2b(u1) << 16);
    uo.y = (unsigned)f2b(u2) | ((unsigned)f2b(u3) << 16);
  }
  *(uint2*)(ub16 + (size_t)m * E_ + e4) = uo;
  // gate
  uint2 g = *(const uint2*)(proj + (size_t)m * E2_ + E_ + e4);
  float g0 = b2f_lo(g.x), g1 = b2f_hi(g.x), g2 = b2f_lo(g.y), g3 = b2f_hi(g.y);
  g0 *= sigm(g0); g1 *= sigm(g1); g2 *= sigm(g2); g3 *= sigm(g3);
  uint2 go;
  go.x = (unsigned)f2b(g0) | ((unsigned)f2b(g1) << 16);
  go.y = (unsigned)f2b(g2) | ((unsigned)f2b(g3) << 16);
  *(uint2*)(gb16 + (size_t)m * E_ + e4) = go;
}

// ---- Parallel (chunked) selective scan --------------------------------------
__global__ __launch_bounds__(256) void k_scanA(const ushort* __restrict__ u, const float* __restrict__ dtb,
                                               const float* __restrict__ xdbc, const float* __restrict__ A_log,
                                               float* __restrict__ Pst, float* __restrict__ Sst) {
  __shared__ float2 s_dtu[2][TS_][16];   // (dt, dt*u)
  __shared__ float  s_b [2][TS_][16];    // B_n
  const int tid = threadIdx.x;
  const int e0 = blockIdx.x << 4;
  const int b  = blockIdx.y;
  const int c  = blockIdx.z;
  const int n  = tid & 15, el = tid >> 4;
  const int e  = e0 + el;
  const float A = -__expf(A_log[e * N_ + n]);
  const int se = tid & 15, st = tid >> 4;

  float r_dt[2], r_b[2];
  ushort r_u[2];
  auto issue = [&](int s) {
    int t0 = c * CL_ + s * TS_;
    #pragma unroll
    for (int j = 0; j < 2; j++) {
      size_t m = (size_t)(b * L_ + t0 + j * 16 + st);
      r_dt[j] = dtb[m * E_ + e0 + se];
      r_u[j]  = u[m * E_ + e0 + se];
    }
    #pragma unroll
    for (int j = 0; j < 2; j++) {
      int idx = j * 256 + tid;
      r_b[j] = xdbc[(size_t)(b * L_ + t0 + (idx >> 4)) * XD_ + R_ + (idx & 15)];
    }
  };
  auto commit = [&](int pb) {
    #pragma unroll
    for (int j = 0; j < 2; j++) {
      int t = j * 16 + st;
      s_dtu[pb][t][se] = make_float2(r_dt[j], r_dt[j] * b2f(r_u[j]));
    }
    #pragma unroll
    for (int j = 0; j < 2; j++) {
      int idx = j * 256 + tid;
      s_b[pb][idx >> 4][idx & 15] = r_b[j];
    }
  };

  issue(0);
  commit(0);
  float hs = 0.0f, pp = 1.0f;
  constexpr int NS = CL_ / TS_;
  for (int s = 0; s < NS; s++) {
    __syncthreads();
    if (s + 1 < NS) issue(s + 1);
    const int pb = s & 1;
    #pragma unroll
    for (int t = 0; t < TS_; t++) {
      float2 dtu = s_dtu[pb][t][el];
      float bv   = s_b[pb][t][n];
      float dA = __expf(dtu.x * A);
      hs = fmaf(hs, dA, dtu.y * bv);
      pp *= dA;
    }
    if (s + 1 < NS) commit((s + 1) & 1);
  }
  size_t o = (((size_t)(b * NCH_ + c) * E_) + e) * N_ + n;
  Pst[o] = pp;
  Sst[o] = hs;
}

__global__ __launch_bounds__(256) void k_scanC(const ushort* __restrict__ u, const float* __restrict__ dtb,
                                               const float* __restrict__ xdbc, const ushort* __restrict__ gb,
                                               const float* __restrict__ A_log, const float* __restrict__ Dp,
                                               const float* __restrict__ Pst, const float* __restrict__ Sst,
                                               ushort* __restrict__ y) {
  __shared__ float2 s_dtu[2][TS_][16];   // (dt, dt*u)
  __shared__ float2 s_bc [2][TS_][16];   // (B_n, C_n)
  __shared__ float2 s_og [2][TS_][16];   // (u*D, silu(gate))
  const int tid = threadIdx.x;
  const int e0 = blockIdx.x << 4;
  const int b  = blockIdx.y;
  const int c  = blockIdx.z;
  const int n  = tid & 15, el = tid >> 4;
  const int e  = e0 + el;
  const float A = -__expf(A_log[e * N_ + n]);
  const int se = tid & 15, st = tid >> 4;
  const float Dv = Dp[e0 + se];

  float r_dt[2], r_bc[4];
  ushort r_u[2], r_g[2];
  auto issue = [&](int s) {
    int t0 = c * CL_ + s * TS_;
    #pragma unroll
    for (int j = 0; j < 2; j++) {
      size_t m = (size_t)(b * L_ + t0 + j * 16 + st);
      r_dt[j] = dtb[m * E_ + e0 + se];
      r_u[j]  = u[m * E_ + e0 + se];
      r_g[j]  = gb[m * E_ + e0 + se];
    }
    #pragma unroll
    for (int j = 0; j < 4; j++) {
      int idx = j * 256 + tid;
      r_bc[j] = xdbc[(size_t)(b * L_ + t0 + (idx >> 5)) * XD_ + R_ + (idx & 31)];
    }
  };
  auto commit = [&](int pb) {
    #pragma unroll
    for (int j = 0; j < 2; j++) {
      int t = j * 16 + st;
      float uf = b2f(r_u[j]);
      s_dtu[pb][t][se] = make_float2(r_dt[j], r_dt[j] * uf);
      s_og[pb][t][se] = make_float2(uf * Dv, b2f(r_g[j]));
    }
    #pragma unroll
    for (int j = 0; j < 4; j++) {
      int idx = j * 256 + tid;
      int t = idx >> 5, col = idx & 31;
      ((float*)&s_bc[pb][t][0])[((col & 15) << 1) + (col >> 4)] = r_bc[j];
    }
  };

  issue(0);
  // inline lookback over predecessor chunk summaries
  float hs = 0.0f;
  for (int cc = 0; cc < c; cc++) {
    size_t o = (((size_t)(b * NCH_ + cc) * E_) + e) * N_ + n;
    hs = fmaf(Pst[o], hs, Sst[o]);
  }
  commit(0);
  constexpr int NS = CL_ / TS_;
  for (int s = 0; s < NS; s++) {
    __syncthreads();
    if (s + 1 < NS) issue(s + 1);
    const int pb = s & 1;
    const int mbase = b * L_ + c * CL_ + s * TS_;
    #pragma unroll
    for (int t = 0; t < TS_; t++) {
      float2 dtu = s_dtu[pb][t][el];
      float2 bc  = s_bc[pb][t][n];
      float dA = __expf(dtu.x * A);
      hs = fmaf(hs, dA, dtu.y * bc.x);
      float p = row_sum16(hs * bc.y);
      if (n == 0) {
        float2 og = s_og[pb][t][el];
        y[(size_t)(mbase + t) * E_ + e] = f2b((p + og.x) * og.y);
      }
    }
    if (s + 1 < NS) commit((s + 1) & 1);
  }
}

// rs[m] = rsqrt(mean(h[m,:]^2)+eps)
__global__ __launch_bounds__(256) void k_rowscale(const float* __restrict__ h, float* __restrict__ rs) {
  __shared__ float sm[4];
  int m = blockIdx.x, tid = threadIdx.x;
  const float* row = h + (size_t)m * D_;
  float v0 = row[tid], v1 = row[tid + 256], v2 = row[tid + 512];
  float s = block_sum(v0 * v0 + v1 * v1 + v2 * v2, sm);
  if (tid == 0) rs[m] = rsqrtf(s * (1.0f / D_) + EPS_);
}

// pooled[b,d] += fnorm_w[d]/L * sum_t h[b,t,d]*rs[b,t]
__global__ __launch_bounds__(256) void k_pool(const float* __restrict__ h, const float* __restrict__ rs,
                                              const float* __restrict__ fw, float* __restrict__ pooled) {
  int d = blockIdx.x * 256 + threadIdx.x;
  int t0 = blockIdx.y * 128;
  int b = blockIdx.z;
  float acc = 0.0f;
  for (int t = t0; t < t0 + 128; t++) {
    int m = b * L_ + t;
    acc = fmaf(h[(size_t)m * D_ + d], rs[m], acc);
  }
  atomicAdd(&pooled[b * D_ + d], acc * fw[d] * (1.0f / L_));
}

// out[b,c] = pooled[b,:] @ cls_w[c,:] + cls_b[c]
__global__ __launch_bounds__(256) void k_logits(const float* __restrict__ pooled, const float* __restrict__ cw,
                                                const float* __restrict__ cb, float* __restrict__ out) {
  int wv = threadIdx.x >> 6, ln = threadIdx.x & 63;
  for (int p = wv; p < B_ * NC_; p += 4) {
    int b = p / NC_, c = p % NC_;
    float s = 0.0f;
    for (int d = ln; d < D_; d += 64) s = fmaf(pooled[b * D_ + d], cw[c * D_ + d], s);
    #pragma unroll
    for (int o = 32; o > 0; o >>= 1) s += __shfl_xor(s, o);
    if (ln == 0) out[p] = s + cb[c];
  }
}

extern "C" void kernel_launch(void* const* d_in, const int* in_sizes, int n_in,
                              void* d_out, int out_size, void* d_ws, size_t ws_size,
                              hipStream_t stream) {
  const float* x       = (const float*)d_in[0];
  const float* proj_w  = (const float*)d_in[1];
  const float* proj_b  = (const float*)d_in[2];
  const float* norm_w  = (const float*)d_in[3];
  const float* in_w    = (const float*)d_in[4];
  const float* conv_w  = (const float*)d_in[5];
  const float* conv_b  = (const float*)d_in[6];
  const float* xproj_w = (const float*)d_in[7];
  const float* dt_w    = (const float*)d_in[8];
  const float* dt_b    = (const float*)d_in[9];
  const float* A_log   = (const float*)d_in[10];
  const float* D_param = (const float*)d_in[11];
  const float* out_w   = (const float*)d_in[12];
  const float* fnorm_w = (const float*)d_in[13];
  const float* cls_w   = (const float*)d_in[14];
  const float* cls_b   = (const float*)d_in[15];
  float* out = (float*)d_out;

  // workspace layout
  float* h      = (float*)d_ws;                         // M*D
  float* xdbc   = h + (size_t)M_ * D_;                  // M*80
  float* dtbuf  = xdbc + (size_t)M_ * XD_;              // M*E
  float* rsb    = dtbuf + (size_t)M_ * E_;              // M
  float* pooled = rsb + M_;                             // B*D
  float* Pst    = pooled + B_ * D_;                     // B*NCH*E*N
  float* Sst    = Pst + (size_t)B_ * NCH_ * E_ * N_;    // B*NCH*E*N
  float* xpart  = Sst + (size_t)B_ * NCH_ * E_ * N_;    // KS*M*80
  ushort* proj_bf = (ushort*)(xpart + (size_t)KS_ * M_ * XD_);  // M*2E bf16
  ushort* hn_bf   = proj_bf + (size_t)M_ * E2_;         // M*D
  ushort* y_bf    = hn_bf + (size_t)M_ * D_;            // M*E
  ushort* ub_bf   = y_bf + (size_t)M_ * E_;             // M*E
  ushort* g_bf    = ub_bf + (size_t)M_ * E_;            // M*E
  ushort* xdbc_bf = g_bf + (size_t)M_ * E_;             // M*64
  ushort* xwb     = xdbc_bf + (size_t)M_ * 64;          // NL*80*E
  ushort* dtwb    = xwb + (size_t)NL_ * XD_ * E_;       // NL*E*64
  ushort* in_wb   = dtwb + (size_t)NL_ * E_ * 64;       // NL*E2*D
  ushort* out_wb  = in_wb + (size_t)NL_ * E2_ * D_;     // NL*D*E

  constexpr int WTOT = WS1_ + WS2_ + WS3_ + WS4_;
  k_wprep<<<(WTOT / 4 + 255) / 256, 256, 0, stream>>>(in_w, out_w, xproj_w, dt_w,
                                                      in_wb, out_wb, xwb, dtwb);

  k_proj<<<dim3(D_ / 256, M_), 256, 0, stream>>>(x, proj_w, proj_b, h);

  for (int i = 0; i < NL_; i++) {
    k_rmsnorm_bf<<<M_, 256, 0, stream>>>(h, norm_w + i * D_, hn_bf);
    k_gemm_bf<64, 128, 3><<<dim3(E2_ / 128, M_ / 64), 256, 0, stream>>>(
        hn_bf, in_wb + (size_t)i * E2_ * D_, proj_bf, nullptr, D_, E2_);
    k_conv2<<<M_, 384, 0, stream>>>(proj_bf, conv_w + i * E_ * 4, conv_b + i * E_, ub_bf, g_bf);
    k_gemm_x<<<dim3(M_ / 64, KS_), 256, 0, stream>>>(ub_bf, xwb + (size_t)i * XD_ * E_, xpart);
    k_xfin<<<M_ * XD_ / 256, 256, 0, stream>>>(xpart, xdbc, xdbc_bf);
    k_gemm_bf<64, 64, 2><<<dim3(E_ / 64, M_ / 64), 256, 0, stream>>>(
        xdbc_bf, dtwb + (size_t)i * E_ * 64, dtbuf, dt_b + i * E_, 64, E_);
    k_scanA<<<dim3(E_ / 16, B_, NCH_), 256, 0, stream>>>(ub_bf, dtbuf, xdbc,
                                                         A_log + (size_t)i * E_ * N_, Pst, Sst);
    k_scanC<<<dim3(E_ / 16, B_, NCH_), 256, 0, stream>>>(ub_bf, dtbuf, xdbc, g_bf,
                                                         A_log + (size_t)i * E_ * N_, D_param + i * E_,
                                                         Pst, Sst, y_bf);
    k_gemm_bf<64, 64, 1><<<dim3(D_ / 64, M_ / 64), 256, 0, stream>>>(
        y_bf, out_wb + (size_t)i * D_ * E_, h, h, E_, D_);
  }

  k_rowscale<<<M_, 256, 0, stream>>>(h, rsb);
  hipMemsetAsync(pooled, 0, (size_t)B_ * D_ * sizeof(float), stream);
  k_pool<<<dim3(D_ / 256, L_ / 128, B_), 256, 0, stream>>>(h, rsb, fnorm_w, pooled);
  k_logits<<<1, 256, 0, stream>>>(pooled, cls_w, cls_b, out);
}